// Round 4
// baseline (190.131 us; speedup 1.0000x reference)
//
#include <hip/hip_runtime.h>
#include <hip/hip_bf16.h>
#include <math.h>

// B=2, C=128, T=5 (Tc=4 ctx), H=W=48, heads=64, PATCH=7 (pad 3), K=196.
#define BATCH 2
#define CCH 128
#define TT 5
#define TC 4
#define HH 48
#define WW 48
#define HWPIX 2304
#define NHEAD 64
#define PAD 3
#define XSTRIDE (TT*HWPIX)      // per-channel stride in x
#define ROWP 54                 // 48 + 2*3 padded rows
#define COLP 56                 // 48 + 2*3 padded cols (+2 align slack)
#define PLANE (ROWP*COLP*NHEAD) // elements per (b,t) plane
#define GOFF (BATCH*TC*PLANE)   // g_b offset from phi_b (elements)

#define NBLK 720                // mega grid size
#define NATT 576                // phase-B tiles

// fused-attn tile geometry: 4 wide x 2 tall pixel tile
#define TW 4
#define TH 2
#define WROWS 8                 // TH + 6
#define WCOLS 10                // TW + 6
#define NRC 80                  // WROWS*WCOLS
#define WELEM (NRC*NHEAD)       // 5120 bf16 per window buffer

// LDS union offsets (bytes)
#define SM_XS    0              // proj: unsigned xs[32*68]   = 8704 B
#define SM_WLA   8704           // proj: uint4 wlA[1024]      = 16384 B
#define SM_WLB   25088          // proj: uint4 wlB[1024]      = 16384 B  -> 41472
#define SM_TOTAL 41472          // attn win = 40960 B aliases from 0

typedef unsigned short bf16_t;

static __device__ __forceinline__ bf16_t f2bf(float f) {
    unsigned u = __float_as_uint(f);
    u += 0x7FFFu + ((u >> 16) & 1u);          // round-to-nearest-even
    return (bf16_t)(u >> 16);
}
static __device__ __forceinline__ float bf_lo(unsigned u) {
    return __uint_as_float(u << 16);
}
static __device__ __forceinline__ float bf_hi(unsigned u) {
    return __uint_as_float(u & 0xFFFF0000u);
}

// v_dot2_f32_bf16 path (hedged: falls back to unpack+fma if unavailable)
#if defined(__has_builtin)
#if __has_builtin(__builtin_amdgcn_fdot2_f32_bf16) && __has_builtin(__builtin_amdgcn_perm)
#define HAVE_DOT2 1
#endif
#endif

#ifdef HAVE_DOT2
typedef __bf16 bf16x2_t __attribute__((ext_vector_type(2)));
static __device__ __forceinline__ float dot2bf(unsigned g2, unsigned a2, float c) {
    return __builtin_amdgcn_fdot2_f32_bf16(
        __builtin_bit_cast(bf16x2_t, g2), __builtin_bit_cast(bf16x2_t, a2), c, false);
}
static __device__ __forceinline__ unsigned perm_lo(unsigned a, unsigned b) {
    return __builtin_amdgcn_perm(a, b, 0x05040100u);
}
static __device__ __forceinline__ unsigned perm_hi(unsigned a, unsigned b) {
    return __builtin_amdgcn_perm(a, b, 0x07060302u);
}
#else
static __device__ __forceinline__ float dot2bf(unsigned g2, unsigned a2, float c) {
    return c + bf_lo(g2) * bf_lo(a2) + bf_hi(g2) * bf_hi(a2);
}
#endif

// ---------------------------------------------------------------------------
// MEGA kernel: phase A = projections (720 tasks, 1/block), SOFTWARE grid
// barrier (plain launch: cooperative launch was rejected under graph capture
// in R3), phase B = fused attention + combine + out-proj + residual (576
// tiles). 720 blocks x 256 thr, 3 blocks/CU (LDS 44.1 KB, VGPR<=168 via
// launch_bounds(256,3)) -> all co-resident (768 capacity); phase-A-only
// blocks arrive at the barrier and exit without spinning.
// ---------------------------------------------------------------------------
__global__ __launch_bounds__(256, 3) void mega_kernel(
    const float* __restrict__ x,
    const float* __restrict__ w_theta,
    const float* __restrict__ w_phi,
    const float* __restrict__ w_g,
    const float* __restrict__ w_out,
    bf16_t* __restrict__ q_b,
    bf16_t* __restrict__ phi_b,     // g planes at phi_b + GOFF
    unsigned* __restrict__ bar,     // zeroed by memset node before launch
    float* __restrict__ out)
{
    __shared__ __align__(16) char smem[SM_TOTAL];
    __shared__ float ls[8][52];
    __shared__ unsigned ls2[8][26];
    __shared__ unsigned prow[26];

    const int bi  = blockIdx.x;
    const int tid = threadIdx.x;

    // =============================== PHASE A ===============================
    {
        unsigned* xs  = (unsigned*)(smem + SM_XS);   // [32 px][68 pitch]
        uint4*    wlA = (uint4*)(smem + SM_WLA);     // [16 ck][64 h]
        uint4*    wlB = (uint4*)(smem + SM_WLB);

        const int bt   = bi / 72;          // 0..9
        const int b    = bt / TT;
        const int t    = bt % TT;
        const int lane = tid & 63;
        const int wv   = tid >> 6;
        const int p0   = (bi % 72) * 32;

        // ---- stage weights from fp32, packing to bf16 pairs ----
        {
            const float* srcA = (t == 0) ? w_theta : w_phi;
#pragma unroll
            for (int i = 0; i < 4; ++i) {
                const int idx = i * 256 + tid;   // 0..1023
                const int h   = idx >> 4;        // 0..63
                const int ck  = idx & 15;        // chunk 0..15
                const float* s = srcA + h * CCH + ck * 8;
                const float4 v0 = *(const float4*)(s);
                const float4 v1 = *(const float4*)(s + 4);
                uint4 o;
                o.x = (unsigned)f2bf(v0.x) | ((unsigned)f2bf(v0.y) << 16);
                o.y = (unsigned)f2bf(v0.z) | ((unsigned)f2bf(v0.w) << 16);
                o.z = (unsigned)f2bf(v1.x) | ((unsigned)f2bf(v1.y) << 16);
                o.w = (unsigned)f2bf(v1.z) | ((unsigned)f2bf(v1.w) << 16);
                wlA[(ck << 6) | h] = o;
            }
            if (t != 0) {
#pragma unroll
                for (int i = 0; i < 4; ++i) {
                    const int idx = i * 256 + tid;
                    const int h   = idx >> 4;
                    const int ck  = idx & 15;
                    const float* s = w_g + h * CCH + ck * 8;
                    const float4 v0 = *(const float4*)(s);
                    const float4 v1 = *(const float4*)(s + 4);
                    uint4 o;
                    o.x = (unsigned)f2bf(v0.x) | ((unsigned)f2bf(v0.y) << 16);
                    o.y = (unsigned)f2bf(v0.z) | ((unsigned)f2bf(v0.w) << 16);
                    o.z = (unsigned)f2bf(v1.x) | ((unsigned)f2bf(v1.y) << 16);
                    o.w = (unsigned)f2bf(v1.z) | ((unsigned)f2bf(v1.w) << 16);
                    wlB[(ck << 6) | h] = o;
                }
            }
        }

        // ---- stage x tile as bf16 pairs (lanes over 32 px: coalesced) ----
        {
            const float* xsrc = x + ((size_t)(b * CCH) * TT + t) * HWPIX + p0;
#pragma unroll
            for (int i = 0; i < 8; ++i) {
                const int idx = i * 256 + tid;  // 0..2047
                const int cp  = idx >> 5;       // c-pair 0..63
                const int px  = idx & 31;
                const float a0 = xsrc[(size_t)(2 * cp)     * XSTRIDE + px];
                const float a1 = xsrc[(size_t)(2 * cp + 1) * XSTRIDE + px];
                xs[px * 68 + cp] = (unsigned)f2bf(a0) | ((unsigned)f2bf(a1) << 16);
            }
        }
        __syncthreads();

        const int pxb = wv * 8;

        if (t == 0) {
            float acc[8];
#pragma unroll
            for (int p = 0; p < 8; ++p) acc[p] = 0.f;
#pragma unroll 4
            for (int ck = 0; ck < 16; ++ck) {
                const uint4 wa = wlA[(ck << 6) | lane];
#pragma unroll
                for (int p = 0; p < 8; ++p) {
                    const uint4 xv = *(const uint4*)&xs[(pxb + p) * 68 + (ck << 2)];
                    acc[p] = dot2bf(wa.x, xv.x, acc[p]);
                    acc[p] = dot2bf(wa.y, xv.y, acc[p]);
                    acc[p] = dot2bf(wa.z, xv.z, acc[p]);
                    acc[p] = dot2bf(wa.w, xv.w, acc[p]);
                }
            }
#pragma unroll
            for (int p = 0; p < 8; ++p)
                q_b[((size_t)b * HWPIX + p0 + pxb + p) * NHEAD + lane] = f2bf(acc[p]);
        } else {
            float accp[8], accg[8];
#pragma unroll
            for (int p = 0; p < 8; ++p) { accp[p] = 0.f; accg[p] = 0.f; }
#pragma unroll 4
            for (int ck = 0; ck < 16; ++ck) {
                const uint4 wa = wlA[(ck << 6) | lane];
                const uint4 wb = wlB[(ck << 6) | lane];
#pragma unroll
                for (int p = 0; p < 8; ++p) {
                    const uint4 xv = *(const uint4*)&xs[(pxb + p) * 68 + (ck << 2)];
                    accp[p] = dot2bf(wa.x, xv.x, accp[p]);
                    accp[p] = dot2bf(wa.y, xv.y, accp[p]);
                    accp[p] = dot2bf(wa.z, xv.z, accp[p]);
                    accp[p] = dot2bf(wa.w, xv.w, accp[p]);
                    accg[p] = dot2bf(wb.x, xv.x, accg[p]);
                    accg[p] = dot2bf(wb.y, xv.y, accg[p]);
                    accg[p] = dot2bf(wb.z, xv.z, accg[p]);
                    accg[p] = dot2bf(wb.w, xv.w, accg[p]);
                }
            }
            const size_t base = (size_t)(b * TC + (t - 1)) * PLANE;
#pragma unroll
            for (int p = 0; p < 8; ++p) {
                const int pix = p0 + pxb + p;
                const int X = pix / WW;
                const int Y = pix % WW;
                const int rs = (X == 0) ? 0 : (X + PAD);
                const int rn = (X == 0 || X == HH - 1) ? (PAD + 1) : 1;
                const int cs = (Y == 0) ? 0 : (Y + PAD);
                const int cn = (Y == 0 || Y == WW - 1) ? (PAD + 1) : 1;
                const bf16_t vp = f2bf(accp[p]);
                const bf16_t vg = f2bf(accg[p]);
                for (int r = 0; r < rn; ++r)
                    for (int c = 0; c < cn; ++c) {
                        const size_t pos = base + ((size_t)(rs + r) * COLP + (cs + c)) * NHEAD + lane;
                        phi_b[pos]        = vp;
                        phi_b[pos + GOFF] = vg;
                    }
            }
        }
    }

    // ---- software grid barrier (device-scope; graph-capture-safe) ----
    __syncthreads();
    if (tid == 0) {
        __threadfence();    // release phase-A stores device-wide (cross-XCD)
        __hip_atomic_fetch_add(bar, 1u, __ATOMIC_RELEASE, __HIP_MEMORY_SCOPE_AGENT);
    }
    if (bi >= NATT) return;            // phase-A-only blocks: arrive & exit
    if (tid == 0) {
        while (__hip_atomic_load(bar, __ATOMIC_ACQUIRE, __HIP_MEMORY_SCOPE_AGENT) < NBLK)
            __builtin_amdgcn_s_sleep(2);
        __threadfence();    // acquire side
    }
    __syncthreads();

    // =============================== PHASE B ===============================
    {
        const bf16_t* pg = phi_b;
        const int px  = tid >> 5;           // 0..7 pixel of tile
        const int sub = tid & 31;
        const int Y0  = (bi % 12) * TW;
        const int X0  = ((bi / 12) % 24) * TH;
        const int b   = bi / 288;
        const int rr  = px >> 2;
        const int cc  = px & 3;
        const int gpix  = (X0 + rr) * WW + Y0 + cc;
        const int pxoff = rr * WCOLS + cc;
        const int oct = sub >> 2;
        const int par = sub & 3;

        // ---- q fragments (64 h = 8 uint4), broadcast across 32 sub-lanes ----
        uint4 qu[8];
        {
            const uint4* qs = (const uint4*)(q_b + ((size_t)b * HWPIX + gpix) * NHEAD);
#pragma unroll
            for (int ch = 0; ch < 8; ++ch) qu[ch] = qs[ch];
        }

        if (tid < 25) {
            const int k0 = 2 * tid;
            const int k1 = (k0 + 1 < 49) ? k0 + 1 : 48;
            const unsigned r0 = (unsigned)((k0 / 7) * WCOLS + (k0 % 7));
            const unsigned r1 = (unsigned)((k1 / 7) * WCOLS + (k1 % 7));
            prow[tid] = r0 | (r1 << 16);
        }

        // ---- per-thread staging offsets: 1280 uint4 per stage = 5/thread ----
        int srcoff[5], lddst[5];
#pragma unroll
        for (int ii = 0; ii < 5; ++ii) {
            const int idx  = ii * 256 + tid;          // 0..1279
            const int isg  = (idx >= 640) ? 1 : 0;    // 0: phi, 1: g
            const int idx2 = idx - (isg ? 640 : 0);
            const int row  = idx2 >> 3;               // 0..79
            const int ch   = idx2 & 7;
            const int i    = row / WCOLS;
            const int c    = row - i * WCOLS;
            srcoff[ii] = isg * GOFF + ((X0 + i) * COLP + Y0 + c) * NHEAD + ch * 8;
            lddst[ii]  = isg * (2 * WELEM) + row * NHEAD + (((ch + row) & 7) << 3);
        }

        bf16_t* winb = (bf16_t*)smem;   // [phi0|phi1|g0|g1], 5120 elems each

        // ---- prologue: stage t=0 into parity 0 ----
        {
            const bf16_t* sp = pg + (size_t)(b * TC) * PLANE;
#pragma unroll
            for (int ii = 0; ii < 5; ++ii) {
                const uint4 v = *(const uint4*)(sp + srcoff[ii]);
                *(uint4*)(winb + lddst[ii]) = v;
            }
        }
        __syncthreads();

        float m_run = -INFINITY, l_run = 0.f;
        float acc[8];
#pragma unroll
        for (int e = 0; e < 8; ++e) acc[e] = 0.f;

        for (int t = 0; t < TC; ++t) {
            const int p = t & 1;

            // ---- issue next-t loads early (hidden under logits+PV) ----
            uint4 stg[5];
            if (t < TC - 1) {
                const bf16_t* sp = pg + (size_t)(b * TC + t + 1) * PLANE;
#pragma unroll
                for (int ii = 0; ii < 5; ++ii)
                    stg[ii] = *(const uint4*)(sp + srcoff[ii]);
            }

            // ---- logits: keys k = sub and sub+32 ----
            const bf16_t* pbase = winb + p * WELEM;
            float v0, v1 = -INFINITY;
            {
                const int k = sub;
                const int i = k / 7, j = k - i * 7;
                const int row = i * WCOLS + j + pxoff;
                const bf16_t* base = pbase + row * NHEAD;
                float s = 0.f;
#pragma unroll
                for (int ch = 0; ch < 8; ++ch) {
                    const uint4 u = *(const uint4*)&base[((ch + row) & 7) << 3];
                    s = dot2bf(u.x, qu[ch].x, s);
                    s = dot2bf(u.y, qu[ch].y, s);
                    s = dot2bf(u.z, qu[ch].z, s);
                    s = dot2bf(u.w, qu[ch].w, s);
                }
                v0 = s * 8.0f;    // * sqrt(64)
            }
            if (sub + 32 < 49) {
                const int k = sub + 32;
                const int i = k / 7, j = k - i * 7;
                const int row = i * WCOLS + j + pxoff;
                const bf16_t* base = pbase + row * NHEAD;
                float s = 0.f;
#pragma unroll
                for (int ch = 0; ch < 8; ++ch) {
                    const uint4 u = *(const uint4*)&base[((ch + row) & 7) << 3];
                    s = dot2bf(u.x, qu[ch].x, s);
                    s = dot2bf(u.y, qu[ch].y, s);
                    s = dot2bf(u.z, qu[ch].z, s);
                    s = dot2bf(u.w, qu[ch].w, s);
                }
                v1 = s * 8.0f;
            }

            // ---- online softmax update (per px-group of 32 lanes) ----
            float mt = fmaxf(v0, v1);
#pragma unroll
            for (int d = 1; d < 32; d <<= 1) mt = fmaxf(mt, __shfl_xor(mt, d));
            const float m_new = fmaxf(m_run, mt);
            const float sc = __expf(m_run - m_new);
            const float e0 = __expf(v0 - m_new);
            float lsum = e0;
            ls[px][sub] = e0;
            if (sub + 32 < 49) {
                const float e1 = __expf(v1 - m_new);
                ls[px][sub + 32] = e1;
                lsum += e1;
            }
#pragma unroll
            for (int d = 1; d < 32; d <<= 1) lsum += __shfl_xor(lsum, d);
            m_run = m_new;
            l_run = l_run * sc + lsum;

            if (sub < 25) {
                const float a0 = ls[px][2 * sub];
                const float a1 = (2 * sub + 1 < 49) ? ls[px][2 * sub + 1] : 0.f;
                ls2[px][sub] = (unsigned)f2bf(a0) | ((unsigned)f2bf(a1) << 16);
            }

            // ---- PV accumulate with rescale ----
#pragma unroll
            for (int e = 0; e < 8; ++e) acc[e] *= sc;
            const bf16_t* gbase = winb + 2 * WELEM + p * WELEM;
#pragma unroll
            for (int mi = 0; mi < 7; ++mi) {
                const int pm = par + 4 * mi;
                if (pm < 25) {
                    const unsigned pr = prow[pm];
                    const int row0 = (int)(pr & 0xFFFFu) + pxoff;
                    const int row1 = (int)(pr >> 16) + pxoff;
                    const uint4 u0 = *(const uint4*)&gbase[row0 * NHEAD + (((oct + row0) & 7) << 3)];
                    const uint4 u1 = *(const uint4*)&gbase[row1 * NHEAD + (((oct + row1) & 7) << 3)];
#ifdef HAVE_DOT2
                    const unsigned a2 = ls2[px][pm];
                    acc[0] = dot2bf(perm_lo(u1.x, u0.x), a2, acc[0]);
                    acc[1] = dot2bf(perm_hi(u1.x, u0.x), a2, acc[1]);
                    acc[2] = dot2bf(perm_lo(u1.y, u0.y), a2, acc[2]);
                    acc[3] = dot2bf(perm_hi(u1.y, u0.y), a2, acc[3]);
                    acc[4] = dot2bf(perm_lo(u1.z, u0.z), a2, acc[4]);
                    acc[5] = dot2bf(perm_hi(u1.z, u0.z), a2, acc[5]);
                    acc[6] = dot2bf(perm_lo(u1.w, u0.w), a2, acc[6]);
                    acc[7] = dot2bf(perm_hi(u1.w, u0.w), a2, acc[7]);
#else
                    const float a0 = ls[px][2 * pm];
                    const float a1 = (2 * pm + 1 < 49) ? ls[px][2 * pm + 1] : 0.f;
                    acc[0] = fmaf(a1, bf_lo(u1.x), fmaf(a0, bf_lo(u0.x), acc[0]));
                    acc[1] = fmaf(a1, bf_hi(u1.x), fmaf(a0, bf_hi(u0.x), acc[1]));
                    acc[2] = fmaf(a1, bf_lo(u1.y), fmaf(a0, bf_lo(u0.y), acc[2]));
                    acc[3] = fmaf(a1, bf_hi(u1.y), fmaf(a0, bf_hi(u0.y), acc[3]));
                    acc[4] = fmaf(a1, bf_lo(u1.z), fmaf(a0, bf_lo(u0.z), acc[4]));
                    acc[5] = fmaf(a1, bf_hi(u1.z), fmaf(a0, bf_hi(u0.z), acc[5]));
                    acc[6] = fmaf(a1, bf_lo(u1.w), fmaf(a0, bf_lo(u0.w), acc[6]));
                    acc[7] = fmaf(a1, bf_hi(u1.w), fmaf(a0, bf_hi(u0.w), acc[7]));
#endif
                }
            }

            // ---- write-late: next-t windows into alternate buffers ----
            if (t < TC - 1) {
                bf16_t* dp = winb + (p ^ 1) * WELEM;   // g offset baked in lddst
#pragma unroll
                for (int ii = 0; ii < 5; ++ii)
                    *(uint4*)(dp + lddst[ii]) = stg[ii];
            }
            __syncthreads();
        }

        // ---- reduce over par (4 key-subsets), normalize ----
#pragma unroll
        for (int e = 0; e < 8; ++e) {
            acc[e] += __shfl_xor(acc[e], 1);
            acc[e] += __shfl_xor(acc[e], 2);
        }
        const float inv = 1.0f / l_run;

        // ---- epilogue: alias win LDS as w_out tile + y tile ----
        float* wo_s = (float*)smem;                        // [128][68] = 34816 B
        float* y_s  = (float*)(smem + 128 * 68 * 4);       // [8][68]   =  2176 B

#pragma unroll
        for (int ii = 0; ii < 8; ++ii) {
            const int idx = ii * 256 + tid;    // 0..2047
            const int c   = idx >> 4;
            const int hq  = idx & 15;
            const float4 v = *(const float4*)(w_out + (size_t)c * NHEAD + hq * 4);
            *(float4*)&wo_s[c * 68 + hq * 4] = v;
        }
        if (par == 0) {
            const float4 o0 = make_float4(acc[0] * inv, acc[1] * inv, acc[2] * inv, acc[3] * inv);
            const float4 o1 = make_float4(acc[4] * inv, acc[5] * inv, acc[6] * inv, acc[7] * inv);
            *(float4*)&y_s[px * 68 + oct * 8]     = o0;
            *(float4*)&y_s[px * 68 + oct * 8 + 4] = o1;
        }
        __syncthreads();

        // ---- out-projection + residual ----
        {
            const int px2 = tid & 7;
            const int cl  = tid >> 3;          // 0..31
            const int rr2 = px2 >> 2, cc2 = px2 & 3;
            const int gpix2 = (X0 + rr2) * WW + Y0 + cc2;
            float o[4] = {0.f, 0.f, 0.f, 0.f};
#pragma unroll
            for (int h0 = 0; h0 < 16; ++h0) {
                const float4 yv = *(const float4*)&y_s[px2 * 68 + h0 * 4];
#pragma unroll
                for (int it = 0; it < 4; ++it) {
                    const float4 wv = *(const float4*)&wo_s[(cl + 32 * it) * 68 + h0 * 4];
                    o[it] = fmaf(wv.x, yv.x, o[it]);
                    o[it] = fmaf(wv.y, yv.y, o[it]);
                    o[it] = fmaf(wv.z, yv.z, o[it]);
                    o[it] = fmaf(wv.w, yv.w, o[it]);
                }
            }
#pragma unroll
            for (int it = 0; it < 4; ++it) {
                const size_t ccg = (size_t)(b * CCH + cl + 32 * it);
                const float xi = x[ccg * TT * HWPIX + gpix2];
                out[ccg * HWPIX + gpix2] = xi + o[it];
            }
        }
    }
}

// ---------------------------------------------------------------------------
extern "C" void kernel_launch(void* const* d_in, const int* in_sizes, int n_in,
                              void* d_out, int out_size, void* d_ws, size_t ws_size,
                              hipStream_t stream)
{
    const float* x       = (const float*)d_in[0];
    const float* w_theta = (const float*)d_in[1];
    const float* w_phi   = (const float*)d_in[2];
    const float* w_g     = (const float*)d_in[3];
    const float* w_out   = (const float*)d_in[4];
    float* out = (float*)d_out;

    bf16_t*   q_b   = (bf16_t*)d_ws;                        // 294912 elems
    bf16_t*   phi_b = q_b + (size_t)BATCH * HWPIX * NHEAD;  // 2x 1548288 elems
    unsigned* bar   = (unsigned*)(phi_b + 2 * (size_t)GOFF);

    hipMemsetAsync(bar, 0, 64, stream);   // zero the barrier counter (graph node)

    mega_kernel<<<NBLK, 256, 0, stream>>>(x, w_theta, w_phi, w_g, w_out,
                                          q_b, phi_b, bar, out);
}

// Round 5
// 113.003 us; speedup vs baseline: 1.6825x; 1.6825x over previous
//
#include <hip/hip_runtime.h>
#include <hip/hip_bf16.h>
#include <math.h>

// B=2, C=128, T=5 (Tc=4 ctx), H=W=48, heads=64, PATCH=7 (pad 3), K=196.
#define BATCH 2
#define CCH 128
#define TT 5
#define TC 4
#define HH 48
#define WW 48
#define HWPIX 2304
#define NHEAD 64
#define PAD 3
#define XSTRIDE (TT*HWPIX)      // per-channel stride in x
#define ROWP 54                 // 48 + 2*3 padded rows
#define COLP 56                 // 48 + 2*3 padded cols (+2 align slack)
#define PLANE (ROWP*COLP*NHEAD) // elements per (b,t) plane
#define GOFF (BATCH*TC*PLANE)   // g_b offset from phi_b (elements)

// fused-attn tile geometry: 4 wide x 2 tall pixel tile
#define TW 4
#define TH 2
#define WROWS 8                 // TH + 6
#define WCOLS 10                // TW + 6
#define NRC 80                  // WROWS*WCOLS
#define WELEM (NRC*NHEAD)       // 5120 bf16 per window buffer

typedef unsigned short bf16_t;

static __device__ __forceinline__ bf16_t f2bf(float f) {
    unsigned u = __float_as_uint(f);
    u += 0x7FFFu + ((u >> 16) & 1u);          // round-to-nearest-even
    return (bf16_t)(u >> 16);
}
static __device__ __forceinline__ float bf_lo(unsigned u) {
    return __uint_as_float(u << 16);
}
static __device__ __forceinline__ float bf_hi(unsigned u) {
    return __uint_as_float(u & 0xFFFF0000u);
}

// v_dot2_f32_bf16 path (hedged: falls back to unpack+fma if unavailable)
#if defined(__has_builtin)
#if __has_builtin(__builtin_amdgcn_fdot2_f32_bf16) && __has_builtin(__builtin_amdgcn_perm)
#define HAVE_DOT2 1
#endif
#endif

#ifdef HAVE_DOT2
typedef __bf16 bf16x2_t __attribute__((ext_vector_type(2)));
static __device__ __forceinline__ float dot2bf(unsigned g2, unsigned a2, float c) {
    return __builtin_amdgcn_fdot2_f32_bf16(
        __builtin_bit_cast(bf16x2_t, g2), __builtin_bit_cast(bf16x2_t, a2), c, false);
}
static __device__ __forceinline__ unsigned perm_lo(unsigned a, unsigned b) {
    return __builtin_amdgcn_perm(a, b, 0x05040100u);
}
static __device__ __forceinline__ unsigned perm_hi(unsigned a, unsigned b) {
    return __builtin_amdgcn_perm(a, b, 0x07060302u);
}
#else
static __device__ __forceinline__ float dot2bf(unsigned g2, unsigned a2, float c) {
    return c + bf_lo(g2) * bf_lo(a2) + bf_hi(g2) * bf_hi(a2);
}
#endif

// ---------------------------------------------------------------------------
// K1: projections (R2 version, unchanged). 32 px per block, weights packed
// on the fly to bf16 pairs in LDS, fully LDS-resident dot2 inner loop.
// ---------------------------------------------------------------------------
__global__ __launch_bounds__(256) void proj_kernel(
    const float* __restrict__ x,
    const float* __restrict__ w_theta,
    const float* __restrict__ w_phi,
    const float* __restrict__ w_g,
    bf16_t* __restrict__ q_b,
    bf16_t* __restrict__ phi_b,
    bf16_t* __restrict__ g_b)
{
    __shared__ unsigned xs[32 * 68];    // 8.5 KB (bf16 c-pairs, pitch 68)
    __shared__ uint4 wlA[1024];         // 16 KB  [ck 0..15][h 0..63]
    __shared__ uint4 wlB[1024];         // 16 KB

    const int bt   = blockIdx.y;        // 0..9
    const int b    = bt / TT;
    const int t    = bt % TT;
    const int tid  = threadIdx.x;
    const int lane = tid & 63;
    const int wv   = tid >> 6;
    const int p0   = blockIdx.x * 32;

    // ---- stage weights from fp32, packing to bf16 pairs ----
    {
        const float* srcA = (t == 0) ? w_theta : w_phi;
#pragma unroll
        for (int i = 0; i < 4; ++i) {
            const int idx = i * 256 + tid;   // 0..1023
            const int h   = idx >> 4;        // 0..63
            const int ck  = idx & 15;        // chunk 0..15
            const float* s = srcA + h * CCH + ck * 8;
            const float4 v0 = *(const float4*)(s);
            const float4 v1 = *(const float4*)(s + 4);
            uint4 o;
            o.x = (unsigned)f2bf(v0.x) | ((unsigned)f2bf(v0.y) << 16);
            o.y = (unsigned)f2bf(v0.z) | ((unsigned)f2bf(v0.w) << 16);
            o.z = (unsigned)f2bf(v1.x) | ((unsigned)f2bf(v1.y) << 16);
            o.w = (unsigned)f2bf(v1.z) | ((unsigned)f2bf(v1.w) << 16);
            wlA[(ck << 6) | h] = o;
        }
        if (t != 0) {
#pragma unroll
            for (int i = 0; i < 4; ++i) {
                const int idx = i * 256 + tid;
                const int h   = idx >> 4;
                const int ck  = idx & 15;
                const float* s = w_g + h * CCH + ck * 8;
                const float4 v0 = *(const float4*)(s);
                const float4 v1 = *(const float4*)(s + 4);
                uint4 o;
                o.x = (unsigned)f2bf(v0.x) | ((unsigned)f2bf(v0.y) << 16);
                o.y = (unsigned)f2bf(v0.z) | ((unsigned)f2bf(v0.w) << 16);
                o.z = (unsigned)f2bf(v1.x) | ((unsigned)f2bf(v1.y) << 16);
                o.w = (unsigned)f2bf(v1.z) | ((unsigned)f2bf(v1.w) << 16);
                wlB[(ck << 6) | h] = o;
            }
        }
    }

    // ---- stage x tile as bf16 pairs (lanes over 32 px: 128B coalesced) ----
    {
        const float* xsrc = x + ((size_t)(b * CCH) * TT + t) * HWPIX + p0;
#pragma unroll
        for (int i = 0; i < 8; ++i) {
            const int idx = i * 256 + tid;  // 0..2047
            const int cp  = idx >> 5;       // c-pair 0..63
            const int px  = idx & 31;
            const float a0 = xsrc[(size_t)(2 * cp)     * XSTRIDE + px];
            const float a1 = xsrc[(size_t)(2 * cp + 1) * XSTRIDE + px];
            xs[px * 68 + cp] = (unsigned)f2bf(a0) | ((unsigned)f2bf(a1) << 16);
        }
    }
    __syncthreads();

    const int pxb = wv * 8;

    if (t == 0) {
        float acc[8];
#pragma unroll
        for (int p = 0; p < 8; ++p) acc[p] = 0.f;
#pragma unroll 4
        for (int ck = 0; ck < 16; ++ck) {
            const uint4 wa = wlA[(ck << 6) | lane];
#pragma unroll
            for (int p = 0; p < 8; ++p) {
                const uint4 xv = *(const uint4*)&xs[(pxb + p) * 68 + (ck << 2)];
                acc[p] = dot2bf(wa.x, xv.x, acc[p]);
                acc[p] = dot2bf(wa.y, xv.y, acc[p]);
                acc[p] = dot2bf(wa.z, xv.z, acc[p]);
                acc[p] = dot2bf(wa.w, xv.w, acc[p]);
            }
        }
#pragma unroll
        for (int p = 0; p < 8; ++p)
            q_b[((size_t)b * HWPIX + p0 + pxb + p) * NHEAD + lane] = f2bf(acc[p]);
    } else {
        float accp[8], accg[8];
#pragma unroll
        for (int p = 0; p < 8; ++p) { accp[p] = 0.f; accg[p] = 0.f; }
#pragma unroll 4
        for (int ck = 0; ck < 16; ++ck) {
            const uint4 wa = wlA[(ck << 6) | lane];
            const uint4 wb = wlB[(ck << 6) | lane];
#pragma unroll
            for (int p = 0; p < 8; ++p) {
                const uint4 xv = *(const uint4*)&xs[(pxb + p) * 68 + (ck << 2)];
                accp[p] = dot2bf(wa.x, xv.x, accp[p]);
                accp[p] = dot2bf(wa.y, xv.y, accp[p]);
                accp[p] = dot2bf(wa.z, xv.z, accp[p]);
                accp[p] = dot2bf(wa.w, xv.w, accp[p]);
                accg[p] = dot2bf(wb.x, xv.x, accg[p]);
                accg[p] = dot2bf(wb.y, xv.y, accg[p]);
                accg[p] = dot2bf(wb.z, xv.z, accg[p]);
                accg[p] = dot2bf(wb.w, xv.w, accg[p]);
            }
        }
        const size_t base = (size_t)(b * TC + (t - 1)) * PLANE;
#pragma unroll
        for (int p = 0; p < 8; ++p) {
            const int pix = p0 + pxb + p;
            const int X = pix / WW;
            const int Y = pix % WW;
            const int rs = (X == 0) ? 0 : (X + PAD);
            const int rn = (X == 0 || X == HH - 1) ? (PAD + 1) : 1;
            const int cs = (Y == 0) ? 0 : (Y + PAD);
            const int cn = (Y == 0 || Y == WW - 1) ? (PAD + 1) : 1;
            const bf16_t vp = f2bf(accp[p]);
            const bf16_t vg = f2bf(accg[p]);
            for (int r = 0; r < rn; ++r)
                for (int c = 0; c < cn; ++c) {
                    const size_t pos = base + ((size_t)(rs + r) * COLP + (cs + c)) * NHEAD + lane;
                    phi_b[pos] = vp;
                    g_b[pos]   = vg;
                }
        }
    }
}

// ---------------------------------------------------------------------------
// K2: FUSED attention + combine + out-proj + residual — 512-thread version.
// Same 576 4x2-px tiles as R2, but 64 lanes (= one wave) per pixel: doubles
// resident waves/CU on the grid-limited launch (R4 counters showed 26%
// occupancy / 10% VALUBusy -> latency-bound, wave-starved). Logits: 1 key
// per lane; softmax reduce across the full wave; exp values flow through
// registers+shfl (ls[] scratch eliminated). PV: 8 head-octets x 8 key-pair
// subsets. Epilogue: 2 channels/thread.
// ---------------------------------------------------------------------------
__global__ __launch_bounds__(512, 4) void attn_fused_kernel(
    const float* __restrict__ x,
    const bf16_t* __restrict__ q_b,
    const bf16_t* __restrict__ pg,      // phi planes; g planes at pg + GOFF
    const float* __restrict__ w_out,
    float* __restrict__ out)
{
    __shared__ __align__(16) char smem[4 * WELEM * 2];  // 40960 B win / alias
    __shared__ unsigned ls2[8][26];
    __shared__ unsigned prow[26];

    const int tid = threadIdx.x;
    const int px  = tid >> 6;           // 0..7 pixel of tile (= wave id)
    const int sub = tid & 63;
    const int Y0  = blockIdx.x * TW;
    const int X0  = blockIdx.y * TH;
    const int b   = blockIdx.z;
    const int rr  = px >> 2;
    const int cc  = px & 3;
    const int gpix  = (X0 + rr) * WW + Y0 + cc;
    const int pxoff = rr * WCOLS + cc;
    const int oct = sub >> 3;           // 0..7 head octet
    const int par = sub & 7;            // 0..7 key-pair subset

    // ---- q fragments (64 h = 8 uint4), broadcast across the wave ----
    uint4 qu[8];
    {
        const uint4* qs = (const uint4*)(q_b + ((size_t)b * HWPIX + gpix) * NHEAD);
#pragma unroll
        for (int ch = 0; ch < 8; ++ch) qu[ch] = qs[ch];
    }

    if (tid < 25) {
        const int k0 = 2 * tid;
        const int k1 = (k0 + 1 < 49) ? k0 + 1 : 48;
        const unsigned r0 = (unsigned)((k0 / 7) * WCOLS + (k0 % 7));
        const unsigned r1 = (unsigned)((k1 / 7) * WCOLS + (k1 % 7));
        prow[tid] = r0 | (r1 << 16);
    }

    // ---- per-thread staging offsets: 1280 uint4 per stage over 512 thr ----
    int srcoff[3], lddst[3];
#pragma unroll
    for (int ii = 0; ii < 3; ++ii) {
        const int idx = ii * 512 + tid;           // 0..1535
        if (idx < 1280) {
            const int isg  = (idx >= 640) ? 1 : 0;    // 0: phi, 1: g
            const int idx2 = idx - (isg ? 640 : 0);
            const int row  = idx2 >> 3;               // 0..79
            const int ch   = idx2 & 7;
            const int i    = row / WCOLS;
            const int c    = row - i * WCOLS;
            srcoff[ii] = isg * GOFF + ((X0 + i) * COLP + Y0 + c) * NHEAD + ch * 8;
            lddst[ii]  = isg * (2 * WELEM) + row * NHEAD + (((ch + row) & 7) << 3);
        } else { srcoff[ii] = 0; lddst[ii] = -1; }
    }

    bf16_t* winb = (bf16_t*)smem;   // [phi0|phi1|g0|g1], 5120 elems each

    // ---- prologue: stage t=0 into parity 0 ----
    {
        const bf16_t* sp = pg + (size_t)(b * TC) * PLANE;
#pragma unroll
        for (int ii = 0; ii < 3; ++ii) {
            if (lddst[ii] >= 0) {
                const uint4 v = *(const uint4*)(sp + srcoff[ii]);
                *(uint4*)(winb + lddst[ii]) = v;
            }
        }
    }
    __syncthreads();

    float m_run = -INFINITY, l_run = 0.f;
    float acc[8];
#pragma unroll
    for (int e = 0; e < 8; ++e) acc[e] = 0.f;

    for (int t = 0; t < TC; ++t) {
        const int p = t & 1;

        // ---- issue next-t loads early (hidden under logits+PV) ----
        uint4 stg[3];
        if (t < TC - 1) {
            const bf16_t* sp = pg + (size_t)(b * TC + t + 1) * PLANE;
#pragma unroll
            for (int ii = 0; ii < 3; ++ii)
                if (lddst[ii] >= 0) stg[ii] = *(const uint4*)(sp + srcoff[ii]);
        }

        // ---- logits: one key per lane (keys 0..48; lanes 49..63 idle) ----
        const bf16_t* pbase = winb + p * WELEM;
        float v0 = -INFINITY;
        if (sub < 49) {
            const int i = sub / 7, j = sub - i * 7;
            const int row = i * WCOLS + j + pxoff;
            const bf16_t* base = pbase + row * NHEAD;
            float s = 0.f;
#pragma unroll
            for (int ch = 0; ch < 8; ++ch) {
                const uint4 u = *(const uint4*)&base[((ch + row) & 7) << 3];
                s = dot2bf(u.x, qu[ch].x, s);
                s = dot2bf(u.y, qu[ch].y, s);
                s = dot2bf(u.z, qu[ch].z, s);
                s = dot2bf(u.w, qu[ch].w, s);
            }
            v0 = s * 8.0f;    // * sqrt(64)
        }

        // ---- online softmax update (full-wave reduce) ----
        float mt = v0;
#pragma unroll
        for (int d = 1; d < 64; d <<= 1) mt = fmaxf(mt, __shfl_xor(mt, d));
        const float m_new = fmaxf(m_run, mt);
        const float sc = __expf(m_run - m_new);
        const float e0 = (sub < 49) ? __expf(v0 - m_new) : 0.f;
        float lsum = e0;
#pragma unroll
        for (int d = 1; d < 64; d <<= 1) lsum += __shfl_xor(lsum, d);
        m_run = m_new;
        l_run = l_run * sc + lsum;

        // ---- pack exp-weight pairs via shfl (uniform exec), lanes<25 write ----
        const float a0 = __shfl(e0, (2 * sub) & 63);
        const float a1 = __shfl(e0, (2 * sub + 1) & 63);
        if (sub < 25)
            ls2[px][sub] = (unsigned)f2bf(a0) | ((unsigned)f2bf(a1) << 16);

        // ---- PV accumulate with rescale: 8 octets x 8 subsets ----
#pragma unroll
        for (int e = 0; e < 8; ++e) acc[e] *= sc;
        const bf16_t* gbase = winb + 2 * WELEM + p * WELEM;
#pragma unroll
        for (int mi = 0; mi < 4; ++mi) {
            const int pm = par + 8 * mi;
            if (pm < 25) {
                const unsigned pr = prow[pm];
                const int row0 = (int)(pr & 0xFFFFu) + pxoff;
                const int row1 = (int)(pr >> 16) + pxoff;
                const uint4 u0 = *(const uint4*)&gbase[row0 * NHEAD + (((oct + row0) & 7) << 3)];
                const uint4 u1 = *(const uint4*)&gbase[row1 * NHEAD + (((oct + row1) & 7) << 3)];
#ifdef HAVE_DOT2
                const unsigned a2 = ls2[px][pm];
                acc[0] = dot2bf(perm_lo(u1.x, u0.x), a2, acc[0]);
                acc[1] = dot2bf(perm_hi(u1.x, u0.x), a2, acc[1]);
                acc[2] = dot2bf(perm_lo(u1.y, u0.y), a2, acc[2]);
                acc[3] = dot2bf(perm_hi(u1.y, u0.y), a2, acc[3]);
                acc[4] = dot2bf(perm_lo(u1.z, u0.z), a2, acc[4]);
                acc[5] = dot2bf(perm_hi(u1.z, u0.z), a2, acc[5]);
                acc[6] = dot2bf(perm_lo(u1.w, u0.w), a2, acc[6]);
                acc[7] = dot2bf(perm_hi(u1.w, u0.w), a2, acc[7]);
#else
                const unsigned a2 = ls2[px][pm];
                const float b0 = bf_lo(a2), b1 = bf_hi(a2);
                acc[0] = fmaf(b1, bf_lo(u1.x), fmaf(b0, bf_lo(u0.x), acc[0]));
                acc[1] = fmaf(b1, bf_hi(u1.x), fmaf(b0, bf_hi(u0.x), acc[1]));
                acc[2] = fmaf(b1, bf_lo(u1.y), fmaf(b0, bf_lo(u0.y), acc[2]));
                acc[3] = fmaf(b1, bf_hi(u1.y), fmaf(b0, bf_hi(u0.y), acc[3]));
                acc[4] = fmaf(b1, bf_lo(u1.z), fmaf(b0, bf_lo(u0.z), acc[4]));
                acc[5] = fmaf(b1, bf_hi(u1.z), fmaf(b0, bf_hi(u0.z), acc[5]));
                acc[6] = fmaf(b1, bf_lo(u1.w), fmaf(b0, bf_lo(u0.w), acc[6]));
                acc[7] = fmaf(b1, bf_hi(u1.w), fmaf(b0, bf_hi(u0.w), acc[7]));
#endif
            }
        }

        // ---- write-late: next-t windows into alternate buffers ----
        if (t < TC - 1) {
            bf16_t* dp = winb + (p ^ 1) * WELEM;   // g offset baked in lddst
#pragma unroll
            for (int ii = 0; ii < 3; ++ii)
                if (lddst[ii] >= 0) *(uint4*)(dp + lddst[ii]) = stg[ii];
        }
        __syncthreads();
    }

    // ---- reduce over par (8 key-subsets), normalize ----
#pragma unroll
    for (int e = 0; e < 8; ++e) {
        acc[e] += __shfl_xor(acc[e], 1);
        acc[e] += __shfl_xor(acc[e], 2);
        acc[e] += __shfl_xor(acc[e], 4);
    }
    const float inv = 1.0f / l_run;

    // ---- epilogue: alias win LDS as w_out tile + y tile ----
    float* wo_s = (float*)smem;                        // [128][68] = 34816 B
    float* y_s  = (float*)(smem + 128 * 68 * 4);       // [8][68]   =  2176 B

#pragma unroll
    for (int ii = 0; ii < 4; ++ii) {
        const int idx = ii * 512 + tid;    // 0..2047
        const int c   = idx >> 4;
        const int hq  = idx & 15;
        const float4 v = *(const float4*)(w_out + (size_t)c * NHEAD + hq * 4);
        *(float4*)&wo_s[c * 68 + hq * 4] = v;
    }
    if (par == 0) {
        const float4 o0 = make_float4(acc[0] * inv, acc[1] * inv, acc[2] * inv, acc[3] * inv);
        const float4 o1 = make_float4(acc[4] * inv, acc[5] * inv, acc[6] * inv, acc[7] * inv);
        *(float4*)&y_s[px * 68 + oct * 8]     = o0;
        *(float4*)&y_s[px * 68 + oct * 8 + 4] = o1;
    }
    __syncthreads();

    // ---- out-projection + residual: thread = (channel, px), 2 ch each ----
    {
        const int px2 = tid & 7;
        const int cl  = tid >> 3;          // 0..63
        const int rr2 = px2 >> 2, cc2 = px2 & 3;
        const int gpix2 = (X0 + rr2) * WW + Y0 + cc2;
        float o0 = 0.f, o1 = 0.f;
#pragma unroll
        for (int h0 = 0; h0 < 16; ++h0) {
            const float4 yv = *(const float4*)&y_s[px2 * 68 + h0 * 4];
            const float4 w0 = *(const float4*)&wo_s[cl * 68 + h0 * 4];
            const float4 w1 = *(const float4*)&wo_s[(cl + 64) * 68 + h0 * 4];
            o0 = fmaf(w0.x, yv.x, o0); o0 = fmaf(w0.y, yv.y, o0);
            o0 = fmaf(w0.z, yv.z, o0); o0 = fmaf(w0.w, yv.w, o0);
            o1 = fmaf(w1.x, yv.x, o1); o1 = fmaf(w1.y, yv.y, o1);
            o1 = fmaf(w1.z, yv.z, o1); o1 = fmaf(w1.w, yv.w, o1);
        }
        const size_t c0 = (size_t)(b * CCH + cl);
        const size_t c1 = (size_t)(b * CCH + cl + 64);
        out[c0 * HWPIX + gpix2] = x[c0 * TT * HWPIX + gpix2] + o0;
        out[c1 * HWPIX + gpix2] = x[c1 * TT * HWPIX + gpix2] + o1;
    }
}

// ---------------------------------------------------------------------------
extern "C" void kernel_launch(void* const* d_in, const int* in_sizes, int n_in,
                              void* d_out, int out_size, void* d_ws, size_t ws_size,
                              hipStream_t stream)
{
    const float* x       = (const float*)d_in[0];
    const float* w_theta = (const float*)d_in[1];
    const float* w_phi   = (const float*)d_in[2];
    const float* w_g     = (const float*)d_in[3];
    const float* w_out   = (const float*)d_in[4];
    float* out = (float*)d_out;

    bf16_t* q_b   = (bf16_t*)d_ws;                        // 294912 elems
    bf16_t* phi_b = q_b + (size_t)BATCH * HWPIX * NHEAD;  // 2x 1548288 elems
    bf16_t* g_b   = phi_b + (size_t)GOFF;

    dim3 g1(HWPIX / 32, BATCH * TT);            // (72, 10)
    proj_kernel<<<g1, 256, 0, stream>>>(x, w_theta, w_phi, w_g, q_b, phi_b, g_b);

    dim3 g2(WW / TW, HH / TH, BATCH);           // (12, 24, 2) = 576 blocks
    attn_fused_kernel<<<g2, 512, 0, stream>>>(x, q_b, phi_b, w_out, out);
}

// Round 6
// 104.072 us; speedup vs baseline: 1.8269x; 1.0858x over previous
//
#include <hip/hip_runtime.h>
#include <hip/hip_bf16.h>
#include <math.h>

// B=2, C=128, T=5 (Tc=4 ctx), H=W=48, heads=64, PATCH=7 (pad 3), K=196.
#define BATCH 2
#define CCH 128
#define TT 5
#define TC 4
#define HH 48
#define WW 48
#define HWPIX 2304
#define NHEAD 64
#define PAD 3
#define XSTRIDE (TT*HWPIX)      // per-channel stride in x
#define ROWP 54                 // 48 + 2*3 padded rows
#define COLP 56                 // 48 + 2*3 padded cols (+2 align slack)
#define PLANE (ROWP*COLP*NHEAD) // elements per (b,t) plane
#define GOFF (BATCH*TC*PLANE)   // g_b offset from phi_b (elements)

// fused-attn tile geometry: 4 wide x 2 tall pixel tile
#define TW 4
#define TH 2
#define WROWS 8                 // TH + 6
#define WCOLS 10                // TW + 6
#define NRC 80                  // WROWS*WCOLS
#define WELEM (NRC*NHEAD)       // 5120 bf16 per window buffer

typedef unsigned short bf16_t;

static __device__ __forceinline__ bf16_t f2bf(float f) {
    unsigned u = __float_as_uint(f);
    u += 0x7FFFu + ((u >> 16) & 1u);          // round-to-nearest-even
    return (bf16_t)(u >> 16);
}
static __device__ __forceinline__ float bf_lo(unsigned u) {
    return __uint_as_float(u << 16);
}
static __device__ __forceinline__ float bf_hi(unsigned u) {
    return __uint_as_float(u & 0xFFFF0000u);
}

// v_dot2_f32_bf16 path (hedged: falls back to unpack+fma if unavailable)
#if defined(__has_builtin)
#if __has_builtin(__builtin_amdgcn_fdot2_f32_bf16) && __has_builtin(__builtin_amdgcn_perm)
#define HAVE_DOT2 1
#endif
#endif

#ifdef HAVE_DOT2
typedef __bf16 bf16x2_t __attribute__((ext_vector_type(2)));
static __device__ __forceinline__ float dot2bf(unsigned g2, unsigned a2, float c) {
    return __builtin_amdgcn_fdot2_f32_bf16(
        __builtin_bit_cast(bf16x2_t, g2), __builtin_bit_cast(bf16x2_t, a2), c, false);
}
static __device__ __forceinline__ unsigned perm_lo(unsigned a, unsigned b) {
    return __builtin_amdgcn_perm(a, b, 0x05040100u);
}
static __device__ __forceinline__ unsigned perm_hi(unsigned a, unsigned b) {
    return __builtin_amdgcn_perm(a, b, 0x07060302u);
}
#else
static __device__ __forceinline__ float dot2bf(unsigned g2, unsigned a2, float c) {
    return c + bf_lo(g2) * bf_lo(a2) + bf_hi(g2) * bf_hi(a2);
}
#endif

// ---------------------------------------------------------------------------
// K1: projections (R2 version, unchanged). 32 px per block, weights packed
// on the fly to bf16 pairs in LDS, fully LDS-resident dot2 inner loop.
// ---------------------------------------------------------------------------
__global__ __launch_bounds__(256) void proj_kernel(
    const float* __restrict__ x,
    const float* __restrict__ w_theta,
    const float* __restrict__ w_phi,
    const float* __restrict__ w_g,
    bf16_t* __restrict__ q_b,
    bf16_t* __restrict__ phi_b,
    bf16_t* __restrict__ g_b)
{
    __shared__ unsigned xs[32 * 68];    // 8.5 KB (bf16 c-pairs, pitch 68)
    __shared__ uint4 wlA[1024];         // 16 KB  [ck 0..15][h 0..63]
    __shared__ uint4 wlB[1024];         // 16 KB

    const int bt   = blockIdx.y;        // 0..9
    const int b    = bt / TT;
    const int t    = bt % TT;
    const int tid  = threadIdx.x;
    const int lane = tid & 63;
    const int wv   = tid >> 6;
    const int p0   = blockIdx.x * 32;

    // ---- stage weights from fp32, packing to bf16 pairs ----
    {
        const float* srcA = (t == 0) ? w_theta : w_phi;
#pragma unroll
        for (int i = 0; i < 4; ++i) {
            const int idx = i * 256 + tid;   // 0..1023
            const int h   = idx >> 4;        // 0..63
            const int ck  = idx & 15;        // chunk 0..15
            const float* s = srcA + h * CCH + ck * 8;
            const float4 v0 = *(const float4*)(s);
            const float4 v1 = *(const float4*)(s + 4);
            uint4 o;
            o.x = (unsigned)f2bf(v0.x) | ((unsigned)f2bf(v0.y) << 16);
            o.y = (unsigned)f2bf(v0.z) | ((unsigned)f2bf(v0.w) << 16);
            o.z = (unsigned)f2bf(v1.x) | ((unsigned)f2bf(v1.y) << 16);
            o.w = (unsigned)f2bf(v1.z) | ((unsigned)f2bf(v1.w) << 16);
            wlA[(ck << 6) | h] = o;
        }
        if (t != 0) {
#pragma unroll
            for (int i = 0; i < 4; ++i) {
                const int idx = i * 256 + tid;
                const int h   = idx >> 4;
                const int ck  = idx & 15;
                const float* s = w_g + h * CCH + ck * 8;
                const float4 v0 = *(const float4*)(s);
                const float4 v1 = *(const float4*)(s + 4);
                uint4 o;
                o.x = (unsigned)f2bf(v0.x) | ((unsigned)f2bf(v0.y) << 16);
                o.y = (unsigned)f2bf(v0.z) | ((unsigned)f2bf(v0.w) << 16);
                o.z = (unsigned)f2bf(v1.x) | ((unsigned)f2bf(v1.y) << 16);
                o.w = (unsigned)f2bf(v1.z) | ((unsigned)f2bf(v1.w) << 16);
                wlB[(ck << 6) | h] = o;
            }
        }
    }

    // ---- stage x tile as bf16 pairs (lanes over 32 px: 128B coalesced) ----
    {
        const float* xsrc = x + ((size_t)(b * CCH) * TT + t) * HWPIX + p0;
#pragma unroll
        for (int i = 0; i < 8; ++i) {
            const int idx = i * 256 + tid;  // 0..2047
            const int cp  = idx >> 5;       // c-pair 0..63
            const int px  = idx & 31;
            const float a0 = xsrc[(size_t)(2 * cp)     * XSTRIDE + px];
            const float a1 = xsrc[(size_t)(2 * cp + 1) * XSTRIDE + px];
            xs[px * 68 + cp] = (unsigned)f2bf(a0) | ((unsigned)f2bf(a1) << 16);
        }
    }
    __syncthreads();

    const int pxb = wv * 8;

    if (t == 0) {
        float acc[8];
#pragma unroll
        for (int p = 0; p < 8; ++p) acc[p] = 0.f;
#pragma unroll 4
        for (int ck = 0; ck < 16; ++ck) {
            const uint4 wa = wlA[(ck << 6) | lane];
#pragma unroll
            for (int p = 0; p < 8; ++p) {
                const uint4 xv = *(const uint4*)&xs[(pxb + p) * 68 + (ck << 2)];
                acc[p] = dot2bf(wa.x, xv.x, acc[p]);
                acc[p] = dot2bf(wa.y, xv.y, acc[p]);
                acc[p] = dot2bf(wa.z, xv.z, acc[p]);
                acc[p] = dot2bf(wa.w, xv.w, acc[p]);
            }
        }
#pragma unroll
        for (int p = 0; p < 8; ++p)
            q_b[((size_t)b * HWPIX + p0 + pxb + p) * NHEAD + lane] = f2bf(acc[p]);
    } else {
        float accp[8], accg[8];
#pragma unroll
        for (int p = 0; p < 8; ++p) { accp[p] = 0.f; accg[p] = 0.f; }
#pragma unroll 4
        for (int ck = 0; ck < 16; ++ck) {
            const uint4 wa = wlA[(ck << 6) | lane];
            const uint4 wb = wlB[(ck << 6) | lane];
#pragma unroll
            for (int p = 0; p < 8; ++p) {
                const uint4 xv = *(const uint4*)&xs[(pxb + p) * 68 + (ck << 2)];
                accp[p] = dot2bf(wa.x, xv.x, accp[p]);
                accp[p] = dot2bf(wa.y, xv.y, accp[p]);
                accp[p] = dot2bf(wa.z, xv.z, accp[p]);
                accp[p] = dot2bf(wa.w, xv.w, accp[p]);
                accg[p] = dot2bf(wb.x, xv.x, accg[p]);
                accg[p] = dot2bf(wb.y, xv.y, accg[p]);
                accg[p] = dot2bf(wb.z, xv.z, accg[p]);
                accg[p] = dot2bf(wb.w, xv.w, accg[p]);
            }
        }
        const size_t base = (size_t)(b * TC + (t - 1)) * PLANE;
#pragma unroll
        for (int p = 0; p < 8; ++p) {
            const int pix = p0 + pxb + p;
            const int X = pix / WW;
            const int Y = pix % WW;
            const int rs = (X == 0) ? 0 : (X + PAD);
            const int rn = (X == 0 || X == HH - 1) ? (PAD + 1) : 1;
            const int cs = (Y == 0) ? 0 : (Y + PAD);
            const int cn = (Y == 0 || Y == WW - 1) ? (PAD + 1) : 1;
            const bf16_t vp = f2bf(accp[p]);
            const bf16_t vg = f2bf(accg[p]);
            for (int r = 0; r < rn; ++r)
                for (int c = 0; c < cn; ++c) {
                    const size_t pos = base + ((size_t)(rs + r) * COLP + (cs + c)) * NHEAD + lane;
                    phi_b[pos] = vp;
                    g_b[pos]   = vg;
                }
        }
    }
}

// ---------------------------------------------------------------------------
// K2: FUSED attention + combine + out-proj + residual (R2 structure).
// R6 changes, all targeting the per-wave SERIAL critical path (R4/R5
// falsified occupancy theory): (1) deferred sum — per-lane l partial,
// ONE 5-shfl reduce after the t-loop instead of per-t; (2) defer-max
// (THR=8) — skip the 5-shfl max reduce + rescale when __all(pmax<=m+8);
// (3) w_out register-prefetch at entry, LDS write in epilogue (T14).
// ---------------------------------------------------------------------------
__global__ __launch_bounds__(256) void attn_fused_kernel(
    const float* __restrict__ x,
    const bf16_t* __restrict__ q_b,
    const bf16_t* __restrict__ pg,      // phi planes; g planes at pg + GOFF
    const float* __restrict__ w_out,
    float* __restrict__ out)
{
    __shared__ __align__(16) char smem[4 * WELEM * 2];  // 40960 B win / alias
    __shared__ float ls[8][52];
    __shared__ unsigned ls2[8][26];
    __shared__ unsigned prow[26];

    const int tid = threadIdx.x;
    const int px  = tid >> 5;           // 0..7 pixel of tile
    const int sub = tid & 31;
    const int Y0  = blockIdx.x * TW;
    const int X0  = blockIdx.y * TH;
    const int b   = blockIdx.z;
    const int rr  = px >> 2;
    const int cc  = px & 3;
    const int gpix  = (X0 + rr) * WW + Y0 + cc;
    const int pxoff = rr * WCOLS + cc;
    const int oct = sub >> 2;
    const int par = sub & 3;

    // ---- w_out register-prefetch (issued now, waited on in epilogue) ----
    float4 wo_r[8];
#pragma unroll
    for (int ii = 0; ii < 8; ++ii) {
        const int idx = ii * 256 + tid;    // 0..2047
        wo_r[ii] = *(const float4*)(w_out + (size_t)(idx >> 4) * NHEAD + (idx & 15) * 4);
    }

    // ---- q fragments (64 h = 8 uint4), broadcast across 32 sub-lanes ----
    uint4 qu[8];
    {
        const uint4* qs = (const uint4*)(q_b + ((size_t)b * HWPIX + gpix) * NHEAD);
#pragma unroll
        for (int ch = 0; ch < 8; ++ch) qu[ch] = qs[ch];
    }

    if (tid < 25) {
        const int k0 = 2 * tid;
        const int k1 = (k0 + 1 < 49) ? k0 + 1 : 48;
        const unsigned r0 = (unsigned)((k0 / 7) * WCOLS + (k0 % 7));
        const unsigned r1 = (unsigned)((k1 / 7) * WCOLS + (k1 % 7));
        prow[tid] = r0 | (r1 << 16);
    }

    // ---- per-thread staging offsets: 1280 uint4 per stage = 5/thread ----
    int srcoff[5], lddst[5];
#pragma unroll
    for (int ii = 0; ii < 5; ++ii) {
        const int idx  = ii * 256 + tid;          // 0..1279
        const int isg  = (idx >= 640) ? 1 : 0;    // 0: phi, 1: g
        const int idx2 = idx - (isg ? 640 : 0);
        const int row  = idx2 >> 3;               // 0..79
        const int ch   = idx2 & 7;
        const int i    = row / WCOLS;
        const int c    = row - i * WCOLS;
        srcoff[ii] = isg * GOFF + ((X0 + i) * COLP + Y0 + c) * NHEAD + ch * 8;
        lddst[ii]  = isg * (2 * WELEM) + row * NHEAD + (((ch + row) & 7) << 3);
    }

    bf16_t* winb = (bf16_t*)smem;   // [phi0 | phi1 | g0 | g1], 5120 elems each

    // ---- prologue: stage t=0 into parity 0 ----
    {
        const bf16_t* sp = pg + (size_t)(b * TC) * PLANE;
#pragma unroll
        for (int ii = 0; ii < 5; ++ii) {
            const uint4 v = *(const uint4*)(sp + srcoff[ii]);
            *(uint4*)(winb + lddst[ii]) = v;
        }
    }
    __syncthreads();

    float m_run = -INFINITY, l_part = 0.f;
    float acc[8];
#pragma unroll
    for (int e = 0; e < 8; ++e) acc[e] = 0.f;

    for (int t = 0; t < TC; ++t) {
        const int p = t & 1;

        // ---- issue next-t loads early (hidden under logits+PV) ----
        uint4 stg[5];
        if (t < TC - 1) {
            const bf16_t* sp = pg + (size_t)(b * TC + t + 1) * PLANE;
#pragma unroll
            for (int ii = 0; ii < 5; ++ii)
                stg[ii] = *(const uint4*)(sp + srcoff[ii]);
        }

        // ---- logits: keys k = sub and sub+32 ----
        const bf16_t* pbase = winb + p * WELEM;
        float v0, v1 = -INFINITY;
        {
            const int k = sub;
            const int i = k / 7, j = k - i * 7;
            const int row = i * WCOLS + j + pxoff;
            const bf16_t* base = pbase + row * NHEAD;
            float s = 0.f;
#pragma unroll
            for (int ch = 0; ch < 8; ++ch) {
                const uint4 u = *(const uint4*)&base[((ch + row) & 7) << 3];
                s = dot2bf(u.x, qu[ch].x, s);
                s = dot2bf(u.y, qu[ch].y, s);
                s = dot2bf(u.z, qu[ch].z, s);
                s = dot2bf(u.w, qu[ch].w, s);
            }
            v0 = s * 8.0f;    // * sqrt(64)
        }
        if (sub + 32 < 49) {
            const int k = sub + 32;
            const int i = k / 7, j = k - i * 7;
            const int row = i * WCOLS + j + pxoff;
            const bf16_t* base = pbase + row * NHEAD;
            float s = 0.f;
#pragma unroll
            for (int ch = 0; ch < 8; ++ch) {
                const uint4 u = *(const uint4*)&base[((ch + row) & 7) << 3];
                s = dot2bf(u.x, qu[ch].x, s);
                s = dot2bf(u.y, qu[ch].y, s);
                s = dot2bf(u.z, qu[ch].z, s);
                s = dot2bf(u.w, qu[ch].w, s);
            }
            v1 = s * 8.0f;
        }

        // ---- online softmax, defer-max (THR=8): skip reduce+rescale when
        //      the lane-local tile max stays within m_run+8 (wave-wide test,
        //      conservative across the 2 px-groups sharing the wave) ----
        const float pmax = fmaxf(v0, v1);
        if (!__all(pmax <= m_run + 8.0f)) {
            float mt = pmax;
#pragma unroll
            for (int d = 1; d < 32; d <<= 1) mt = fmaxf(mt, __shfl_xor(mt, d));
            const float m_new = fmaxf(m_run, mt);
            const float sc = __expf(m_run - m_new);
#pragma unroll
            for (int e = 0; e < 8; ++e) acc[e] *= sc;
            l_part *= sc;
            m_run = m_new;
        }
        const float e0 = __expf(v0 - m_run);
        ls[px][sub] = e0;
        l_part += e0;
        if (sub + 32 < 49) {
            const float e1 = __expf(v1 - m_run);
            ls[px][sub + 32] = e1;
            l_part += e1;
        }

        if (sub < 25) {
            const float a0 = ls[px][2 * sub];
            const float a1 = (2 * sub + 1 < 49) ? ls[px][2 * sub + 1] : 0.f;
            ls2[px][sub] = (unsigned)f2bf(a0) | ((unsigned)f2bf(a1) << 16);
        }

        // ---- PV accumulate ----
        const bf16_t* gbase = winb + 2 * WELEM + p * WELEM;
#pragma unroll
        for (int mi = 0; mi < 7; ++mi) {
            const int pm = par + 4 * mi;
            if (pm < 25) {
                const unsigned pr = prow[pm];
                const int row0 = (int)(pr & 0xFFFFu) + pxoff;
                const int row1 = (int)(pr >> 16) + pxoff;
                const uint4 u0 = *(const uint4*)&gbase[row0 * NHEAD + (((oct + row0) & 7) << 3)];
                const uint4 u1 = *(const uint4*)&gbase[row1 * NHEAD + (((oct + row1) & 7) << 3)];
#ifdef HAVE_DOT2
                const unsigned a2 = ls2[px][pm];
                acc[0] = dot2bf(perm_lo(u1.x, u0.x), a2, acc[0]);
                acc[1] = dot2bf(perm_hi(u1.x, u0.x), a2, acc[1]);
                acc[2] = dot2bf(perm_lo(u1.y, u0.y), a2, acc[2]);
                acc[3] = dot2bf(perm_hi(u1.y, u0.y), a2, acc[3]);
                acc[4] = dot2bf(perm_lo(u1.z, u0.z), a2, acc[4]);
                acc[5] = dot2bf(perm_hi(u1.z, u0.z), a2, acc[5]);
                acc[6] = dot2bf(perm_lo(u1.w, u0.w), a2, acc[6]);
                acc[7] = dot2bf(perm_hi(u1.w, u0.w), a2, acc[7]);
#else
                const float a0 = ls[px][2 * pm];
                const float a1 = (2 * pm + 1 < 49) ? ls[px][2 * pm + 1] : 0.f;
                acc[0] = fmaf(a1, bf_lo(u1.x), fmaf(a0, bf_lo(u0.x), acc[0]));
                acc[1] = fmaf(a1, bf_hi(u1.x), fmaf(a0, bf_hi(u0.x), acc[1]));
                acc[2] = fmaf(a1, bf_lo(u1.y), fmaf(a0, bf_lo(u0.y), acc[2]));
                acc[3] = fmaf(a1, bf_hi(u1.y), fmaf(a0, bf_hi(u0.y), acc[3]));
                acc[4] = fmaf(a1, bf_lo(u1.z), fmaf(a0, bf_lo(u0.z), acc[4]));
                acc[5] = fmaf(a1, bf_hi(u1.z), fmaf(a0, bf_hi(u0.z), acc[5]));
                acc[6] = fmaf(a1, bf_lo(u1.w), fmaf(a0, bf_lo(u0.w), acc[6]));
                acc[7] = fmaf(a1, bf_hi(u1.w), fmaf(a0, bf_hi(u0.w), acc[7]));
#endif
            }
        }

        // ---- write-late: next-t windows into alternate buffers ----
        if (t < TC - 1) {
            bf16_t* dp = winb + (p ^ 1) * WELEM;   // g offset baked into lddst
#pragma unroll
            for (int ii = 0; ii < 5; ++ii)
                *(uint4*)(dp + lddst[ii]) = stg[ii];
        }
        __syncthreads();
    }

    // ---- deferred l reduce (once, 5 shfl), then par reduce of acc ----
#pragma unroll
    for (int d = 1; d < 32; d <<= 1) l_part += __shfl_xor(l_part, d);
#pragma unroll
    for (int e = 0; e < 8; ++e) {
        acc[e] += __shfl_xor(acc[e], 1);
        acc[e] += __shfl_xor(acc[e], 2);
    }
    const float inv = 1.0f / l_part;

    // ---- epilogue: alias win LDS as w_out tile + y tile ----
    float* wo_s = (float*)smem;                        // [128][68] = 34816 B
    float* y_s  = (float*)(smem + 128 * 68 * 4);       // [8][68]   =  2176 B

#pragma unroll
    for (int ii = 0; ii < 8; ++ii) {
        const int idx = ii * 256 + tid;    // 0..2047
        *(float4*)&wo_s[(idx >> 4) * 68 + (idx & 15) * 4] = wo_r[ii];
    }
    if (par == 0) {
        const float4 o0 = make_float4(acc[0] * inv, acc[1] * inv, acc[2] * inv, acc[3] * inv);
        const float4 o1 = make_float4(acc[4] * inv, acc[5] * inv, acc[6] * inv, acc[7] * inv);
        *(float4*)&y_s[px * 68 + oct * 8]     = o0;
        *(float4*)&y_s[px * 68 + oct * 8 + 4] = o1;
    }
    __syncthreads();

    // ---- out-projection + residual ----
    {
        const int px2 = tid & 7;
        const int cl  = tid >> 3;          // 0..31
        const int rr2 = px2 >> 2, cc2 = px2 & 3;
        const int gpix2 = (X0 + rr2) * WW + Y0 + cc2;
        float o[4] = {0.f, 0.f, 0.f, 0.f};
#pragma unroll
        for (int h0 = 0; h0 < 16; ++h0) {
            const float4 yv = *(const float4*)&y_s[px2 * 68 + h0 * 4];
#pragma unroll
            for (int it = 0; it < 4; ++it) {
                const float4 wv = *(const float4*)&wo_s[(cl + 32 * it) * 68 + h0 * 4];
                o[it] = fmaf(wv.x, yv.x, o[it]);
                o[it] = fmaf(wv.y, yv.y, o[it]);
                o[it] = fmaf(wv.z, yv.z, o[it]);
                o[it] = fmaf(wv.w, yv.w, o[it]);
            }
        }
#pragma unroll
        for (int it = 0; it < 4; ++it) {
            const size_t ccg = (size_t)(b * CCH + cl + 32 * it);
            const float xi = x[ccg * TT * HWPIX + gpix2];
            out[ccg * HWPIX + gpix2] = xi + o[it];
        }
    }
}

// ---------------------------------------------------------------------------
extern "C" void kernel_launch(void* const* d_in, const int* in_sizes, int n_in,
                              void* d_out, int out_size, void* d_ws, size_t ws_size,
                              hipStream_t stream)
{
    const float* x       = (const float*)d_in[0];
    const float* w_theta = (const float*)d_in[1];
    const float* w_phi   = (const float*)d_in[2];
    const float* w_g     = (const float*)d_in[3];
    const float* w_out   = (const float*)d_in[4];
    float* out = (float*)d_out;

    bf16_t* q_b   = (bf16_t*)d_ws;                        // 294912 elems
    bf16_t* phi_b = q_b + (size_t)BATCH * HWPIX * NHEAD;  // 2x 1548288 elems
    bf16_t* g_b   = phi_b + (size_t)GOFF;

    dim3 g1(HWPIX / 32, BATCH * TT);            // (72, 10)
    proj_kernel<<<g1, 256, 0, stream>>>(x, w_theta, w_phi, w_g, q_b, phi_b, g_b);

    dim3 g2(WW / TW, HH / TH, BATCH);           // (12, 24, 2) = 576 blocks
    attn_fused_kernel<<<g2, 256, 0, stream>>>(x, q_b, phi_b, w_out, out);
}

// Round 7
// 95.553 us; speedup vs baseline: 1.9898x; 1.0892x over previous
//
#include <hip/hip_runtime.h>
#include <hip/hip_bf16.h>
#include <math.h>

// B=2, C=128, T=5 (Tc=4 ctx), H=W=48, heads=64, PATCH=7 (pad 3), K=196.
#define BATCH 2
#define CCH 128
#define TT 5
#define TC 4
#define HH 48
#define WW 48
#define HWPIX 2304
#define NHEAD 64
#define PAD 3
#define XSTRIDE (TT*HWPIX)      // per-channel stride in x
#define PLANE (HWPIX*NHEAD)     // elements per UNPADDED (b,t) phi/g plane
#define GOFF (BATCH*TC*PLANE)   // g planes offset from phi planes (elements)

// fused-attn tile geometry: 4 wide x 2 tall pixel tile
#define TW 4
#define TH 2
#define WROWS 8                 // TH + 6
#define WCOLS 10               // TW + 6
#define NRC 80                  // WROWS*WCOLS
#define WELEM (NRC*NHEAD)       // 5120 bf16 per window buffer

typedef unsigned short bf16_t;

static __device__ __forceinline__ bf16_t f2bf(float f) {
    unsigned u = __float_as_uint(f);
    u += 0x7FFFu + ((u >> 16) & 1u);          // round-to-nearest-even
    return (bf16_t)(u >> 16);
}
static __device__ __forceinline__ float bf_lo(unsigned u) {
    return __uint_as_float(u << 16);
}
static __device__ __forceinline__ float bf_hi(unsigned u) {
    return __uint_as_float(u & 0xFFFF0000u);
}
static __device__ __forceinline__ int iclamp(int v, int lo, int hi) {
    return v < lo ? lo : (v > hi ? hi : v);
}

// v_dot2_f32_bf16 path (hedged: falls back to unpack+fma if unavailable)
#if defined(__has_builtin)
#if __has_builtin(__builtin_amdgcn_fdot2_f32_bf16) && __has_builtin(__builtin_amdgcn_perm)
#define HAVE_DOT2 1
#endif
#endif

#ifdef HAVE_DOT2
typedef __bf16 bf16x2_t __attribute__((ext_vector_type(2)));
static __device__ __forceinline__ float dot2bf(unsigned g2, unsigned a2, float c) {
    return __builtin_amdgcn_fdot2_f32_bf16(
        __builtin_bit_cast(bf16x2_t, g2), __builtin_bit_cast(bf16x2_t, a2), c, false);
}
static __device__ __forceinline__ unsigned perm_lo(unsigned a, unsigned b) {
    return __builtin_amdgcn_perm(a, b, 0x05040100u);
}
static __device__ __forceinline__ unsigned perm_hi(unsigned a, unsigned b) {
    return __builtin_amdgcn_perm(a, b, 0x07060302u);
}
#else
static __device__ __forceinline__ float dot2bf(unsigned g2, unsigned a2, float c) {
    return c + bf_lo(g2) * bf_lo(a2) + bf_hi(g2) * bf_hi(a2);
}
#endif

// ---------------------------------------------------------------------------
// K1: projections. R7 change: phi/g stored UNPADDED [2304][64] — replicate
// padding moved to attn's staging-offset precompute (free there). Store path
// is now 8 uniform coalesced 128B stores per thread, no border loops,
// write traffic -31%.
// ---------------------------------------------------------------------------
__global__ __launch_bounds__(256) void proj_kernel(
    const float* __restrict__ x,
    const float* __restrict__ w_theta,
    const float* __restrict__ w_phi,
    const float* __restrict__ w_g,
    bf16_t* __restrict__ q_b,
    bf16_t* __restrict__ phi_b,
    bf16_t* __restrict__ g_b)
{
    __shared__ unsigned xs[32 * 68];    // 8.5 KB (bf16 c-pairs, pitch 68)
    __shared__ uint4 wlA[1024];         // 16 KB  [ck 0..15][h 0..63]
    __shared__ uint4 wlB[1024];         // 16 KB

    const int bt   = blockIdx.y;        // 0..9
    const int b    = bt / TT;
    const int t    = bt % TT;
    const int tid  = threadIdx.x;
    const int lane = tid & 63;
    const int wv   = tid >> 6;
    const int p0   = blockIdx.x * 32;

    // ---- stage weights from fp32, packing to bf16 pairs ----
    {
        const float* srcA = (t == 0) ? w_theta : w_phi;
#pragma unroll
        for (int i = 0; i < 4; ++i) {
            const int idx = i * 256 + tid;   // 0..1023
            const int h   = idx >> 4;        // 0..63
            const int ck  = idx & 15;        // chunk 0..15
            const float* s = srcA + h * CCH + ck * 8;
            const float4 v0 = *(const float4*)(s);
            const float4 v1 = *(const float4*)(s + 4);
            uint4 o;
            o.x = (unsigned)f2bf(v0.x) | ((unsigned)f2bf(v0.y) << 16);
            o.y = (unsigned)f2bf(v0.z) | ((unsigned)f2bf(v0.w) << 16);
            o.z = (unsigned)f2bf(v1.x) | ((unsigned)f2bf(v1.y) << 16);
            o.w = (unsigned)f2bf(v1.z) | ((unsigned)f2bf(v1.w) << 16);
            wlA[(ck << 6) | h] = o;
        }
        if (t != 0) {
#pragma unroll
            for (int i = 0; i < 4; ++i) {
                const int idx = i * 256 + tid;
                const int h   = idx >> 4;
                const int ck  = idx & 15;
                const float* s = w_g + h * CCH + ck * 8;
                const float4 v0 = *(const float4*)(s);
                const float4 v1 = *(const float4*)(s + 4);
                uint4 o;
                o.x = (unsigned)f2bf(v0.x) | ((unsigned)f2bf(v0.y) << 16);
                o.y = (unsigned)f2bf(v0.z) | ((unsigned)f2bf(v0.w) << 16);
                o.z = (unsigned)f2bf(v1.x) | ((unsigned)f2bf(v1.y) << 16);
                o.w = (unsigned)f2bf(v1.z) | ((unsigned)f2bf(v1.w) << 16);
                wlB[(ck << 6) | h] = o;
            }
        }
    }

    // ---- stage x tile as bf16 pairs (lanes over 32 px: 128B coalesced) ----
    {
        const float* xsrc = x + ((size_t)(b * CCH) * TT + t) * HWPIX + p0;
#pragma unroll
        for (int i = 0; i < 8; ++i) {
            const int idx = i * 256 + tid;  // 0..2047
            const int cp  = idx >> 5;       // c-pair 0..63
            const int px  = idx & 31;
            const float a0 = xsrc[(size_t)(2 * cp)     * XSTRIDE + px];
            const float a1 = xsrc[(size_t)(2 * cp + 1) * XSTRIDE + px];
            xs[px * 68 + cp] = (unsigned)f2bf(a0) | ((unsigned)f2bf(a1) << 16);
        }
    }
    __syncthreads();

    const int pxb = wv * 8;

    if (t == 0) {
        float acc[8];
#pragma unroll
        for (int p = 0; p < 8; ++p) acc[p] = 0.f;
#pragma unroll 4
        for (int ck = 0; ck < 16; ++ck) {
            const uint4 wa = wlA[(ck << 6) | lane];
#pragma unroll
            for (int p = 0; p < 8; ++p) {
                const uint4 xv = *(const uint4*)&xs[(pxb + p) * 68 + (ck << 2)];
                acc[p] = dot2bf(wa.x, xv.x, acc[p]);
                acc[p] = dot2bf(wa.y, xv.y, acc[p]);
                acc[p] = dot2bf(wa.z, xv.z, acc[p]);
                acc[p] = dot2bf(wa.w, xv.w, acc[p]);
            }
        }
#pragma unroll
        for (int p = 0; p < 8; ++p)
            q_b[((size_t)b * HWPIX + p0 + pxb + p) * NHEAD + lane] = f2bf(acc[p]);
    } else {
        float accp[8], accg[8];
#pragma unroll
        for (int p = 0; p < 8; ++p) { accp[p] = 0.f; accg[p] = 0.f; }
#pragma unroll 4
        for (int ck = 0; ck < 16; ++ck) {
            const uint4 wa = wlA[(ck << 6) | lane];
            const uint4 wb = wlB[(ck << 6) | lane];
#pragma unroll
            for (int p = 0; p < 8; ++p) {
                const uint4 xv = *(const uint4*)&xs[(pxb + p) * 68 + (ck << 2)];
                accp[p] = dot2bf(wa.x, xv.x, accp[p]);
                accp[p] = dot2bf(wa.y, xv.y, accp[p]);
                accp[p] = dot2bf(wa.z, xv.z, accp[p]);
                accp[p] = dot2bf(wa.w, xv.w, accp[p]);
                accg[p] = dot2bf(wb.x, xv.x, accg[p]);
                accg[p] = dot2bf(wb.y, xv.y, accg[p]);
                accg[p] = dot2bf(wb.z, xv.z, accg[p]);
                accg[p] = dot2bf(wb.w, xv.w, accg[p]);
            }
        }
        // ---- unpadded stores: one 128B row per (px, array) ----
        const size_t base = (size_t)(b * TC + (t - 1)) * PLANE;
#pragma unroll
        for (int p = 0; p < 8; ++p) {
            const size_t pos = base + (size_t)(p0 + pxb + p) * NHEAD + lane;
            phi_b[pos] = f2bf(accp[p]);
            g_b[pos]   = f2bf(accg[p]);
        }
    }
}

// ---------------------------------------------------------------------------
// K2: FUSED attention + combine + out-proj + residual (R2 structure, exact).
// R7 changes only: (1) staging offsets clamp to unpadded planes (replicate
// padding realized here, at zero inner-loop cost); (2) s_setprio(1) around
// the logits->softmax->PV compute span (T5: independent staggered blocks =
// the regime where setprio measured +4-7% on attn).
// ---------------------------------------------------------------------------
__global__ __launch_bounds__(256) void attn_fused_kernel(
    const float* __restrict__ x,
    const bf16_t* __restrict__ q_b,
    const bf16_t* __restrict__ pg,      // phi planes; g planes at pg + GOFF
    const float* __restrict__ w_out,
    float* __restrict__ out)
{
    __shared__ __align__(16) char smem[4 * WELEM * 2];  // 40960 B win / alias
    __shared__ float ls[8][52];
    __shared__ unsigned ls2[8][26];
    __shared__ unsigned prow[26];

    const int tid = threadIdx.x;
    const int px  = tid >> 5;           // 0..7 pixel of tile
    const int sub = tid & 31;
    const int Y0  = blockIdx.x * TW;
    const int X0  = blockIdx.y * TH;
    const int b   = blockIdx.z;
    const int rr  = px >> 2;
    const int cc  = px & 3;
    const int gpix  = (X0 + rr) * WW + Y0 + cc;
    const int pxoff = rr * WCOLS + cc;
    const int oct = sub >> 2;
    const int par = sub & 3;

    // ---- q fragments (64 h = 8 uint4), broadcast across 32 sub-lanes ----
    uint4 qu[8];
    {
        const uint4* qs = (const uint4*)(q_b + ((size_t)b * HWPIX + gpix) * NHEAD);
#pragma unroll
        for (int ch = 0; ch < 8; ++ch) qu[ch] = qs[ch];
    }

    if (tid < 25) {
        const int k0 = 2 * tid;
        const int k1 = (k0 + 1 < 49) ? k0 + 1 : 48;
        const unsigned r0 = (unsigned)((k0 / 7) * WCOLS + (k0 % 7));
        const unsigned r1 = (unsigned)((k1 / 7) * WCOLS + (k1 % 7));
        prow[tid] = r0 | (r1 << 16);
    }

    // ---- per-thread staging offsets: 1280 uint4 per stage = 5/thread.
    //      Replicate padding realized here: clamp window coords to [0,47]. ----
    int srcoff[5], lddst[5];
#pragma unroll
    for (int ii = 0; ii < 5; ++ii) {
        const int idx  = ii * 256 + tid;          // 0..1279
        const int isg  = (idx >= 640) ? 1 : 0;    // 0: phi, 1: g
        const int idx2 = idx - (isg ? 640 : 0);
        const int row  = idx2 >> 3;               // 0..79
        const int ch   = idx2 & 7;
        const int i    = row / WCOLS;
        const int c    = row - i * WCOLS;
        const int xr   = iclamp(X0 + i - PAD, 0, HH - 1);
        const int yc   = iclamp(Y0 + c - PAD, 0, WW - 1);
        srcoff[ii] = isg * GOFF + (xr * WW + yc) * NHEAD + ch * 8;
        lddst[ii]  = isg * (2 * WELEM) + row * NHEAD + (((ch + row) & 7) << 3);
    }

    bf16_t* winb = (bf16_t*)smem;   // [phi0 | phi1 | g0 | g1], 5120 elems each

    // ---- prologue: stage t=0 into parity 0 ----
    {
        const bf16_t* sp = pg + (size_t)(b * TC) * PLANE;
#pragma unroll
        for (int ii = 0; ii < 5; ++ii) {
            const uint4 v = *(const uint4*)(sp + srcoff[ii]);
            *(uint4*)(winb + lddst[ii]) = v;
        }
    }
    __syncthreads();

    float m_run = -INFINITY, l_run = 0.f;
    float acc[8];
#pragma unroll
    for (int e = 0; e < 8; ++e) acc[e] = 0.f;

    for (int t = 0; t < TC; ++t) {
        const int p = t & 1;

        // ---- issue next-t loads early (hidden under logits+PV) ----
        uint4 stg[5];
        if (t < TC - 1) {
            const bf16_t* sp = pg + (size_t)(b * TC + t + 1) * PLANE;
#pragma unroll
            for (int ii = 0; ii < 5; ++ii)
                stg[ii] = *(const uint4*)(sp + srcoff[ii]);
        }

        __builtin_amdgcn_s_setprio(1);

        // ---- logits: keys k = sub and sub+32 ----
        const bf16_t* pbase = winb + p * WELEM;
        float v0, v1 = -INFINITY;
        {
            const int k = sub;
            const int i = k / 7, j = k - i * 7;
            const int row = i * WCOLS + j + pxoff;
            const bf16_t* base = pbase + row * NHEAD;
            float s = 0.f;
#pragma unroll
            for (int ch = 0; ch < 8; ++ch) {
                const uint4 u = *(const uint4*)&base[((ch + row) & 7) << 3];
                s = dot2bf(u.x, qu[ch].x, s);
                s = dot2bf(u.y, qu[ch].y, s);
                s = dot2bf(u.z, qu[ch].z, s);
                s = dot2bf(u.w, qu[ch].w, s);
            }
            v0 = s * 8.0f;    // * sqrt(64)
        }
        if (sub + 32 < 49) {
            const int k = sub + 32;
            const int i = k / 7, j = k - i * 7;
            const int row = i * WCOLS + j + pxoff;
            const bf16_t* base = pbase + row * NHEAD;
            float s = 0.f;
#pragma unroll
            for (int ch = 0; ch < 8; ++ch) {
                const uint4 u = *(const uint4*)&base[((ch + row) & 7) << 3];
                s = dot2bf(u.x, qu[ch].x, s);
                s = dot2bf(u.y, qu[ch].y, s);
                s = dot2bf(u.z, qu[ch].z, s);
                s = dot2bf(u.w, qu[ch].w, s);
            }
            v1 = s * 8.0f;
        }

        // ---- online softmax update (per px-group of 32 lanes) ----
        float mt = fmaxf(v0, v1);
#pragma unroll
        for (int d = 1; d < 32; d <<= 1) mt = fmaxf(mt, __shfl_xor(mt, d));
        const float m_new = fmaxf(m_run, mt);
        const float sc = __expf(m_run - m_new);
        const float e0 = __expf(v0 - m_new);
        float lsum = e0;
        ls[px][sub] = e0;
        if (sub + 32 < 49) {
            const float e1 = __expf(v1 - m_new);
            ls[px][sub + 32] = e1;
            lsum += e1;
        }
#pragma unroll
        for (int d = 1; d < 32; d <<= 1) lsum += __shfl_xor(lsum, d);
        m_run = m_new;
        l_run = l_run * sc + lsum;

        if (sub < 25) {
            const float a0 = ls[px][2 * sub];
            const float a1 = (2 * sub + 1 < 49) ? ls[px][2 * sub + 1] : 0.f;
            ls2[px][sub] = (unsigned)f2bf(a0) | ((unsigned)f2bf(a1) << 16);
        }

        // ---- PV accumulate with rescale ----
#pragma unroll
        for (int e = 0; e < 8; ++e) acc[e] *= sc;
        const bf16_t* gbase = winb + 2 * WELEM + p * WELEM;
#pragma unroll
        for (int mi = 0; mi < 7; ++mi) {
            const int pm = par + 4 * mi;
            if (pm < 25) {
                const unsigned pr = prow[pm];
                const int row0 = (int)(pr & 0xFFFFu) + pxoff;
                const int row1 = (int)(pr >> 16) + pxoff;
                const uint4 u0 = *(const uint4*)&winb[2 * WELEM + p * WELEM + row0 * NHEAD + (((oct + row0) & 7) << 3)];
                const uint4 u1 = *(const uint4*)&gbase[row1 * NHEAD + (((oct + row1) & 7) << 3)];
#ifdef HAVE_DOT2
                const unsigned a2 = ls2[px][pm];
                acc[0] = dot2bf(perm_lo(u1.x, u0.x), a2, acc[0]);
                acc[1] = dot2bf(perm_hi(u1.x, u0.x), a2, acc[1]);
                acc[2] = dot2bf(perm_lo(u1.y, u0.y), a2, acc[2]);
                acc[3] = dot2bf(perm_hi(u1.y, u0.y), a2, acc[3]);
                acc[4] = dot2bf(perm_lo(u1.z, u0.z), a2, acc[4]);
                acc[5] = dot2bf(perm_hi(u1.z, u0.z), a2, acc[5]);
                acc[6] = dot2bf(perm_lo(u1.w, u0.w), a2, acc[6]);
                acc[7] = dot2bf(perm_hi(u1.w, u0.w), a2, acc[7]);
#else
                const float a0 = ls[px][2 * pm];
                const float a1 = (2 * pm + 1 < 49) ? ls[px][2 * pm + 1] : 0.f;
                acc[0] = fmaf(a1, bf_lo(u1.x), fmaf(a0, bf_lo(u0.x), acc[0]));
                acc[1] = fmaf(a1, bf_hi(u1.x), fmaf(a0, bf_hi(u0.x), acc[1]));
                acc[2] = fmaf(a1, bf_lo(u1.y), fmaf(a0, bf_lo(u0.y), acc[2]));
                acc[3] = fmaf(a1, bf_hi(u1.y), fmaf(a0, bf_hi(u0.y), acc[3]));
                acc[4] = fmaf(a1, bf_lo(u1.z), fmaf(a0, bf_lo(u0.z), acc[4]));
                acc[5] = fmaf(a1, bf_hi(u1.z), fmaf(a0, bf_hi(u0.z), acc[5]));
                acc[6] = fmaf(a1, bf_lo(u1.w), fmaf(a0, bf_lo(u0.w), acc[6]));
                acc[7] = fmaf(a1, bf_hi(u1.w), fmaf(a0, bf_hi(u0.w), acc[7]));
#endif
            }
        }

        __builtin_amdgcn_s_setprio(0);

        // ---- write-late: next-t windows into alternate buffers ----
        if (t < TC - 1) {
            bf16_t* dp = winb + (p ^ 1) * WELEM;   // g offset baked into lddst
#pragma unroll
            for (int ii = 0; ii < 5; ++ii)
                *(uint4*)(dp + lddst[ii]) = stg[ii];
        }
        __syncthreads();
    }

    // ---- reduce over par (4 key-subsets), normalize ----
#pragma unroll
    for (int e = 0; e < 8; ++e) {
        acc[e] += __shfl_xor(acc[e], 1);
        acc[e] += __shfl_xor(acc[e], 2);
    }
    const float inv = 1.0f / l_run;

    // ---- epilogue: alias win LDS as w_out tile + y tile ----
    float* wo_s = (float*)smem;                        // [128][68] = 34816 B
    float* y_s  = (float*)(smem + 128 * 68 * 4);       // [8][68]   =  2176 B

#pragma unroll
    for (int ii = 0; ii < 8; ++ii) {
        const int idx = ii * 256 + tid;    // 0..2047
        const int c   = idx >> 4;
        const int hq  = idx & 15;
        const float4 v = *(const float4*)(w_out + (size_t)c * NHEAD + hq * 4);
        *(float4*)&wo_s[c * 68 + hq * 4] = v;
    }
    if (par == 0) {
        const float4 o0 = make_float4(acc[0] * inv, acc[1] * inv, acc[2] * inv, acc[3] * inv);
        const float4 o1 = make_float4(acc[4] * inv, acc[5] * inv, acc[6] * inv, acc[7] * inv);
        *(float4*)&y_s[px * 68 + oct * 8]     = o0;
        *(float4*)&y_s[px * 68 + oct * 8 + 4] = o1;
    }
    __syncthreads();

    // ---- out-projection + residual ----
    {
        const int px2 = tid & 7;
        const int cl  = tid >> 3;          // 0..31
        const int rr2 = px2 >> 2, cc2 = px2 & 3;
        const int gpix2 = (X0 + rr2) * WW + Y0 + cc2;
        float o[4] = {0.f, 0.f, 0.f, 0.f};
#pragma unroll
        for (int h0 = 0; h0 < 16; ++h0) {
            const float4 yv = *(const float4*)&y_s[px2 * 68 + h0 * 4];
#pragma unroll
            for (int it = 0; it < 4; ++it) {
                const float4 wv = *(const float4*)&wo_s[(cl + 32 * it) * 68 + h0 * 4];
                o[it] = fmaf(wv.x, yv.x, o[it]);
                o[it] = fmaf(wv.y, yv.y, o[it]);
                o[it] = fmaf(wv.z, yv.z, o[it]);
                o[it] = fmaf(wv.w, yv.w, o[it]);
            }
        }
#pragma unroll
        for (int it = 0; it < 4; ++it) {
            const size_t ccg = (size_t)(b * CCH + cl + 32 * it);
            const float xi = x[ccg * TT * HWPIX + gpix2];
            out[ccg * HWPIX + gpix2] = xi + o[it];
        }
    }
}

// ---------------------------------------------------------------------------
extern "C" void kernel_launch(void* const* d_in, const int* in_sizes, int n_in,
                              void* d_out, int out_size, void* d_ws, size_t ws_size,
                              hipStream_t stream)
{
    const float* x       = (const float*)d_in[0];
    const float* w_theta = (const float*)d_in[1];
    const float* w_phi   = (const float*)d_in[2];
    const float* w_g     = (const float*)d_in[3];
    const float* w_out   = (const float*)d_in[4];
    float* out = (float*)d_out;

    bf16_t* q_b   = (bf16_t*)d_ws;                        // 294912 elems
    bf16_t* phi_b = q_b + (size_t)BATCH * HWPIX * NHEAD;  // 2x 1179648 elems
    bf16_t* g_b   = phi_b + (size_t)GOFF;

    dim3 g1(HWPIX / 32, BATCH * TT);            // (72, 10)
    proj_kernel<<<g1, 256, 0, stream>>>(x, w_theta, w_phi, w_g, q_b, phi_b, g_b);

    dim3 g2(WW / TW, HH / TH, BATCH);           // (12, 24, 2) = 576 blocks
    attn_fused_kernel<<<g2, 256, 0, stream>>>(x, q_b, phi_b, w_out, out);
}

// Round 8
// 88.737 us; speedup vs baseline: 2.1426x; 1.0768x over previous
//
#include <hip/hip_runtime.h>
#include <hip/hip_bf16.h>
#include <math.h>

// B=2, C=128, T=5 (Tc=4 ctx), H=W=48, heads=64, PATCH=7 (pad 3), K=196.
#define BATCH 2
#define CCH 128
#define TT 5
#define TC 4
#define HH 48
#define WW 48
#define HWPIX 2304
#define NHEAD 64
#define PAD 3
#define XSTRIDE (TT*HWPIX)      // per-channel stride in x
#define PLANE (HWPIX*NHEAD)     // elements per UNPADDED (b,t) phi/g plane
#define GOFF (BATCH*TC*PLANE)   // g planes offset from phi planes (elements)

// fused-attn tile geometry: 4 wide x 2 tall pixel tile
#define TW 4
#define TH 2
#define WROWS 8                 // TH + 6
#define WCOLS 10                // TW + 6
#define NRC 80                  // WROWS*WCOLS
#define WELEM (NRC*NHEAD)       // 5120 bf16 per window buffer

#define WPITCH 136              // proj LDS pitch (bf16): 272B rows -> 2-way bank alias (free)

typedef unsigned short bf16_t;

static __device__ __forceinline__ bf16_t f2bf(float f) {
    unsigned u = __float_as_uint(f);
    u += 0x7FFFu + ((u >> 16) & 1u);          // round-to-nearest-even
    return (bf16_t)(u >> 16);
}
static __device__ __forceinline__ float bf_lo(unsigned u) {
    return __uint_as_float(u << 16);
}
static __device__ __forceinline__ float bf_hi(unsigned u) {
    return __uint_as_float(u & 0xFFFF0000u);
}
static __device__ __forceinline__ int iclamp(int v, int lo, int hi) {
    return v < lo ? lo : (v > hi ? hi : v);
}

// v_dot2_f32_bf16 path (hedged: falls back to unpack+fma if unavailable)
#if defined(__has_builtin)
#if __has_builtin(__builtin_amdgcn_fdot2_f32_bf16) && __has_builtin(__builtin_amdgcn_perm)
#define HAVE_DOT2 1
#endif
#endif

#ifdef HAVE_DOT2
typedef __bf16 bf16x2_t __attribute__((ext_vector_type(2)));
static __device__ __forceinline__ float dot2bf(unsigned g2, unsigned a2, float c) {
    return __builtin_amdgcn_fdot2_f32_bf16(
        __builtin_bit_cast(bf16x2_t, g2), __builtin_bit_cast(bf16x2_t, a2), c, false);
}
static __device__ __forceinline__ unsigned perm_lo(unsigned a, unsigned b) {
    return __builtin_amdgcn_perm(a, b, 0x05040100u);
}
static __device__ __forceinline__ unsigned perm_hi(unsigned a, unsigned b) {
    return __builtin_amdgcn_perm(a, b, 0x07060302u);
}
#else
static __device__ __forceinline__ float dot2bf(unsigned g2, unsigned a2, float c) {
    return c + bf_lo(g2) * bf_lo(a2) + bf_hi(g2) * bf_hi(a2);
}
#endif

typedef __attribute__((ext_vector_type(8))) short bf16x8;
typedef __attribute__((ext_vector_type(4))) float f32x4;

// ---------------------------------------------------------------------------
// K1: projections — MFMA version (R8). Same grid (72,10), same staging
// sources, same output formats as R7. K-loop: mfma_f32_16x16x32_bf16,
// A = x-tile [16px x 32k], B = W^T (contiguous 8-bf16 k-chunks from W rows).
// Wave w = (pxtile = w>>1, hgroup = w&1); per proj: 2 h-tiles x 4 K-steps.
// Fragment layouts: A/B row = lane&15, k = (lane>>4)*8; D col=lane&15 (h),
// row=(lane>>4)*4+reg (px) [verified m89/m91/m92 patterns].
// ---------------------------------------------------------------------------
__global__ __launch_bounds__(256) void proj_kernel(
    const float* __restrict__ x,
    const float* __restrict__ w_theta,
    const float* __restrict__ w_phi,
    const float* __restrict__ w_g,
    bf16_t* __restrict__ q_b,
    bf16_t* __restrict__ phi_b,
    bf16_t* __restrict__ g_b)
{
    __shared__ bf16_t xs[32 * WPITCH];      // 8.7 KB  [px][c]
    __shared__ bf16_t wla[64 * WPITCH];     // 17.4 KB [h][c]  theta/phi
    __shared__ bf16_t wlb[64 * WPITCH];     // 17.4 KB [h][c]  g

    const int bt   = blockIdx.y;        // 0..9
    const int b    = bt / TT;
    const int t    = bt % TT;
    const int tid  = threadIdx.x;
    const int lane = tid & 63;
    const int wv   = tid >> 6;
    const int p0   = blockIdx.x * 32;

    // ---- stage weights from fp32, packing to bf16 [h][c] rows ----
    {
        const float* srcA = (t == 0) ? w_theta : w_phi;
#pragma unroll
        for (int i = 0; i < 4; ++i) {
            const int idx = i * 256 + tid;   // 0..1023
            const int h   = idx >> 4;        // 0..63
            const int ck  = idx & 15;        // chunk 0..15
            const float* s = srcA + h * CCH + ck * 8;
            const float4 v0 = *(const float4*)(s);
            const float4 v1 = *(const float4*)(s + 4);
            uint4 o;
            o.x = (unsigned)f2bf(v0.x) | ((unsigned)f2bf(v0.y) << 16);
            o.y = (unsigned)f2bf(v0.z) | ((unsigned)f2bf(v0.w) << 16);
            o.z = (unsigned)f2bf(v1.x) | ((unsigned)f2bf(v1.y) << 16);
            o.w = (unsigned)f2bf(v1.z) | ((unsigned)f2bf(v1.w) << 16);
            *(uint4*)&wla[h * WPITCH + ck * 8] = o;
        }
        if (t != 0) {
#pragma unroll
            for (int i = 0; i < 4; ++i) {
                const int idx = i * 256 + tid;
                const int h   = idx >> 4;
                const int ck  = idx & 15;
                const float* s = w_g + h * CCH + ck * 8;
                const float4 v0 = *(const float4*)(s);
                const float4 v1 = *(const float4*)(s + 4);
                uint4 o;
                o.x = (unsigned)f2bf(v0.x) | ((unsigned)f2bf(v0.y) << 16);
                o.y = (unsigned)f2bf(v0.z) | ((unsigned)f2bf(v0.w) << 16);
                o.z = (unsigned)f2bf(v1.x) | ((unsigned)f2bf(v1.y) << 16);
                o.w = (unsigned)f2bf(v1.z) | ((unsigned)f2bf(v1.w) << 16);
                *(uint4*)&wlb[h * WPITCH + ck * 8] = o;
            }
        }
    }

    // ---- stage x tile as bf16 [px][c] (lanes over 32 px: coalesced) ----
    {
        const float* xsrc = x + ((size_t)(b * CCH) * TT + t) * HWPIX + p0;
#pragma unroll
        for (int i = 0; i < 8; ++i) {
            const int idx = i * 256 + tid;  // 0..2047
            const int cp  = idx >> 5;       // c-pair 0..63
            const int px  = idx & 31;
            const float a0 = xsrc[(size_t)(2 * cp)     * XSTRIDE + px];
            const float a1 = xsrc[(size_t)(2 * cp + 1) * XSTRIDE + px];
            *(unsigned*)&xs[px * WPITCH + 2 * cp] =
                (unsigned)f2bf(a0) | ((unsigned)f2bf(a1) << 16);
        }
    }
    __syncthreads();

    // ---- MFMA K-loop ----
    const int pxt  = wv >> 1;                  // 0..1  (16-px tile)
    const int hg   = wv & 1;                   // 0..1  (32-h group)
    const int arow = pxt * 16 + (lane & 15);
    const int koff = (lane >> 4) * 8;

    bf16x8 afr[4];
#pragma unroll
    for (int kk = 0; kk < 4; ++kk)
        afr[kk] = *(const bf16x8*)&xs[arow * WPITCH + koff + 32 * kk];

    const int hrow = hg * 32 + (lane & 15);    // B-frag LDS row (h)
    const int prow_ = (lane >> 4) * 4;         // D row base (px within tile)
    const int hcol  = lane & 15;               // D col (h within 16-tile)

    if (t == 0) {
#pragma unroll
        for (int ht = 0; ht < 2; ++ht) {
            f32x4 acc = {0.f, 0.f, 0.f, 0.f};
#pragma unroll
            for (int kk = 0; kk < 4; ++kk) {
                const bf16x8 bfr = *(const bf16x8*)&wla[(hrow + 16 * ht) * WPITCH + koff + 32 * kk];
                acc = __builtin_amdgcn_mfma_f32_16x16x32_bf16(afr[kk], bfr, acc, 0, 0, 0);
            }
            const int h = hg * 32 + 16 * ht + hcol;
#pragma unroll
            for (int r = 0; r < 4; ++r) {
                const int px = p0 + pxt * 16 + prow_ + r;
                q_b[((size_t)b * HWPIX + px) * NHEAD + h] = f2bf(acc[r]);
            }
        }
    } else {
        const size_t base = (size_t)(b * TC + (t - 1)) * PLANE;
#pragma unroll
        for (int pr = 0; pr < 2; ++pr) {
            const bf16_t* wl = pr ? wlb : wla;
            bf16_t* dst = pr ? g_b : phi_b;
#pragma unroll
            for (int ht = 0; ht < 2; ++ht) {
                f32x4 acc = {0.f, 0.f, 0.f, 0.f};
#pragma unroll
                for (int kk = 0; kk < 4; ++kk) {
                    const bf16x8 bfr = *(const bf16x8*)&wl[(hrow + 16 * ht) * WPITCH + koff + 32 * kk];
                    acc = __builtin_amdgcn_mfma_f32_16x16x32_bf16(afr[kk], bfr, acc, 0, 0, 0);
                }
                const int h = hg * 32 + 16 * ht + hcol;
#pragma unroll
                for (int r = 0; r < 4; ++r) {
                    const int px = p0 + pxt * 16 + prow_ + r;
                    dst[base + (size_t)px * NHEAD + h] = f2bf(acc[r]);
                }
            }
        }
    }
}

// ---------------------------------------------------------------------------
// K2: FUSED attention + combine + out-proj + residual (R7, verbatim).
// ---------------------------------------------------------------------------
__global__ __launch_bounds__(256) void attn_fused_kernel(
    const float* __restrict__ x,
    const bf16_t* __restrict__ q_b,
    const bf16_t* __restrict__ pg,      // phi planes; g planes at pg + GOFF
    const float* __restrict__ w_out,
    float* __restrict__ out)
{
    __shared__ __align__(16) char smem[4 * WELEM * 2];  // 40960 B win / alias
    __shared__ float ls[8][52];
    __shared__ unsigned ls2[8][26];
    __shared__ unsigned prow[26];

    const int tid = threadIdx.x;
    const int px  = tid >> 5;           // 0..7 pixel of tile
    const int sub = tid & 31;
    const int Y0  = blockIdx.x * TW;
    const int X0  = blockIdx.y * TH;
    const int b   = blockIdx.z;
    const int rr  = px >> 2;
    const int cc  = px & 3;
    const int gpix  = (X0 + rr) * WW + Y0 + cc;
    const int pxoff = rr * WCOLS + cc;
    const int oct = sub >> 2;
    const int par = sub & 3;

    // ---- q fragments (64 h = 8 uint4), broadcast across 32 sub-lanes ----
    uint4 qu[8];
    {
        const uint4* qs = (const uint4*)(q_b + ((size_t)b * HWPIX + gpix) * NHEAD);
#pragma unroll
        for (int ch = 0; ch < 8; ++ch) qu[ch] = qs[ch];
    }

    if (tid < 25) {
        const int k0 = 2 * tid;
        const int k1 = (k0 + 1 < 49) ? k0 + 1 : 48;
        const unsigned r0 = (unsigned)((k0 / 7) * WCOLS + (k0 % 7));
        const unsigned r1 = (unsigned)((k1 / 7) * WCOLS + (k1 % 7));
        prow[tid] = r0 | (r1 << 16);
    }

    // ---- per-thread staging offsets: 1280 uint4 per stage = 5/thread.
    //      Replicate padding realized here: clamp window coords to [0,47]. ----
    int srcoff[5], lddst[5];
#pragma unroll
    for (int ii = 0; ii < 5; ++ii) {
        const int idx  = ii * 256 + tid;          // 0..1279
        const int isg  = (idx >= 640) ? 1 : 0;    // 0: phi, 1: g
        const int idx2 = idx - (isg ? 640 : 0);
        const int row  = idx2 >> 3;               // 0..79
        const int ch   = idx2 & 7;
        const int i    = row / WCOLS;
        const int c    = row - i * WCOLS;
        const int xr   = iclamp(X0 + i - PAD, 0, HH - 1);
        const int yc   = iclamp(Y0 + c - PAD, 0, WW - 1);
        srcoff[ii] = isg * GOFF + (xr * WW + yc) * NHEAD + ch * 8;
        lddst[ii]  = isg * (2 * WELEM) + row * NHEAD + (((ch + row) & 7) << 3);
    }

    bf16_t* winb = (bf16_t*)smem;   // [phi0 | phi1 | g0 | g1], 5120 elems each

    // ---- prologue: stage t=0 into parity 0 ----
    {
        const bf16_t* sp = pg + (size_t)(b * TC) * PLANE;
#pragma unroll
        for (int ii = 0; ii < 5; ++ii) {
            const uint4 v = *(const uint4*)(sp + srcoff[ii]);
            *(uint4*)(winb + lddst[ii]) = v;
        }
    }
    __syncthreads();

    float m_run = -INFINITY, l_run = 0.f;
    float acc[8];
#pragma unroll
    for (int e = 0; e < 8; ++e) acc[e] = 0.f;

    for (int t = 0; t < TC; ++t) {
        const int p = t & 1;

        // ---- issue next-t loads early (hidden under logits+PV) ----
        uint4 stg[5];
        if (t < TC - 1) {
            const bf16_t* sp = pg + (size_t)(b * TC + t + 1) * PLANE;
#pragma unroll
            for (int ii = 0; ii < 5; ++ii)
                stg[ii] = *(const uint4*)(sp + srcoff[ii]);
        }

        __builtin_amdgcn_s_setprio(1);

        // ---- logits: keys k = sub and sub+32 ----
        const bf16_t* pbase = winb + p * WELEM;
        float v0, v1 = -INFINITY;
        {
            const int k = sub;
            const int i = k / 7, j = k - i * 7;
            const int row = i * WCOLS + j + pxoff;
            const bf16_t* base = pbase + row * NHEAD;
            float s = 0.f;
#pragma unroll
            for (int ch = 0; ch < 8; ++ch) {
                const uint4 u = *(const uint4*)&base[((ch + row) & 7) << 3];
                s = dot2bf(u.x, qu[ch].x, s);
                s = dot2bf(u.y, qu[ch].y, s);
                s = dot2bf(u.z, qu[ch].z, s);
                s = dot2bf(u.w, qu[ch].w, s);
            }
            v0 = s * 8.0f;    // * sqrt(64)
        }
        if (sub + 32 < 49) {
            const int k = sub + 32;
            const int i = k / 7, j = k - i * 7;
            const int row = i * WCOLS + j + pxoff;
            const bf16_t* base = pbase + row * NHEAD;
            float s = 0.f;
#pragma unroll
            for (int ch = 0; ch < 8; ++ch) {
                const uint4 u = *(const uint4*)&base[((ch + row) & 7) << 3];
                s = dot2bf(u.x, qu[ch].x, s);
                s = dot2bf(u.y, qu[ch].y, s);
                s = dot2bf(u.z, qu[ch].z, s);
                s = dot2bf(u.w, qu[ch].w, s);
            }
            v1 = s * 8.0f;
        }

        // ---- online softmax update (per px-group of 32 lanes) ----
        float mt = fmaxf(v0, v1);
#pragma unroll
        for (int d = 1; d < 32; d <<= 1) mt = fmaxf(mt, __shfl_xor(mt, d));
        const float m_new = fmaxf(m_run, mt);
        const float sc = __expf(m_run - m_new);
        const float e0 = __expf(v0 - m_new);
        float lsum = e0;
        ls[px][sub] = e0;
        if (sub + 32 < 49) {
            const float e1 = __expf(v1 - m_new);
            ls[px][sub + 32] = e1;
            lsum += e1;
        }
#pragma unroll
        for (int d = 1; d < 32; d <<= 1) lsum += __shfl_xor(lsum, d);
        m_run = m_new;
        l_run = l_run * sc + lsum;

        if (sub < 25) {
            const float a0 = ls[px][2 * sub];
            const float a1 = (2 * sub + 1 < 49) ? ls[px][2 * sub + 1] : 0.f;
            ls2[px][sub] = (unsigned)f2bf(a0) | ((unsigned)f2bf(a1) << 16);
        }

        // ---- PV accumulate with rescale ----
#pragma unroll
        for (int e = 0; e < 8; ++e) acc[e] *= sc;
        const bf16_t* gbase = winb + 2 * WELEM + p * WELEM;
#pragma unroll
        for (int mi = 0; mi < 7; ++mi) {
            const int pm = par + 4 * mi;
            if (pm < 25) {
                const unsigned pr = prow[pm];
                const int row0 = (int)(pr & 0xFFFFu) + pxoff;
                const int row1 = (int)(pr >> 16) + pxoff;
                const uint4 u0 = *(const uint4*)&gbase[row0 * NHEAD + (((oct + row0) & 7) << 3)];
                const uint4 u1 = *(const uint4*)&gbase[row1 * NHEAD + (((oct + row1) & 7) << 3)];
#ifdef HAVE_DOT2
                const unsigned a2 = ls2[px][pm];
                acc[0] = dot2bf(perm_lo(u1.x, u0.x), a2, acc[0]);
                acc[1] = dot2bf(perm_hi(u1.x, u0.x), a2, acc[1]);
                acc[2] = dot2bf(perm_lo(u1.y, u0.y), a2, acc[2]);
                acc[3] = dot2bf(perm_hi(u1.y, u0.y), a2, acc[3]);
                acc[4] = dot2bf(perm_lo(u1.z, u0.z), a2, acc[4]);
                acc[5] = dot2bf(perm_hi(u1.z, u0.z), a2, acc[5]);
                acc[6] = dot2bf(perm_lo(u1.w, u0.w), a2, acc[6]);
                acc[7] = dot2bf(perm_hi(u1.w, u0.w), a2, acc[7]);
#else
                const float a0 = ls[px][2 * pm];
                const float a1 = (2 * pm + 1 < 49) ? ls[px][2 * pm + 1] : 0.f;
                acc[0] = fmaf(a1, bf_lo(u1.x), fmaf(a0, bf_lo(u0.x), acc[0]));
                acc[1] = fmaf(a1, bf_hi(u1.x), fmaf(a0, bf_hi(u0.x), acc[1]));
                acc[2] = fmaf(a1, bf_lo(u1.y), fmaf(a0, bf_lo(u0.y), acc[2]));
                acc[3] = fmaf(a1, bf_hi(u1.y), fmaf(a0, bf_hi(u0.y), acc[3]));
                acc[4] = fmaf(a1, bf_lo(u1.z), fmaf(a0, bf_lo(u0.z), acc[4]));
                acc[5] = fmaf(a1, bf_hi(u1.z), fmaf(a0, bf_hi(u0.z), acc[5]));
                acc[6] = fmaf(a1, bf_lo(u1.w), fmaf(a0, bf_lo(u0.w), acc[6]));
                acc[7] = fmaf(a1, bf_hi(u1.w), fmaf(a0, bf_hi(u0.w), acc[7]));
#endif
            }
        }

        __builtin_amdgcn_s_setprio(0);

        // ---- write-late: next-t windows into alternate buffers ----
        if (t < TC - 1) {
            bf16_t* dp = winb + (p ^ 1) * WELEM;   // g offset baked into lddst
#pragma unroll
            for (int ii = 0; ii < 5; ++ii)
                *(uint4*)(dp + lddst[ii]) = stg[ii];
        }
        __syncthreads();
    }

    // ---- reduce over par (4 key-subsets), normalize ----
#pragma unroll
    for (int e = 0; e < 8; ++e) {
        acc[e] += __shfl_xor(acc[e], 1);
        acc[e] += __shfl_xor(acc[e], 2);
    }
    const float inv = 1.0f / l_run;

    // ---- epilogue: alias win LDS as w_out tile + y tile ----
    float* wo_s = (float*)smem;                        // [128][68] = 34816 B
    float* y_s  = (float*)(smem + 128 * 68 * 4);       // [8][68]   =  2176 B

#pragma unroll
    for (int ii = 0; ii < 8; ++ii) {
        const int idx = ii * 256 + tid;    // 0..2047
        const int c   = idx >> 4;
        const int hq  = idx & 15;
        const float4 v = *(const float4*)(w_out + (size_t)c * NHEAD + hq * 4);
        *(float4*)&wo_s[c * 68 + hq * 4] = v;
    }
    if (par == 0) {
        const float4 o0 = make_float4(acc[0] * inv, acc[1] * inv, acc[2] * inv, acc[3] * inv);
        const float4 o1 = make_float4(acc[4] * inv, acc[5] * inv, acc[6] * inv, acc[7] * inv);
        *(float4*)&y_s[px * 68 + oct * 8]     = o0;
        *(float4*)&y_s[px * 68 + oct * 8 + 4] = o1;
    }
    __syncthreads();

    // ---- out-projection + residual ----
    {
        const int px2 = tid & 7;
        const int cl  = tid >> 3;          // 0..31
        const int rr2 = px2 >> 2, cc2 = px2 & 3;
        const int gpix2 = (X0 + rr2) * WW + Y0 + cc2;
        float o[4] = {0.f, 0.f, 0.f, 0.f};
#pragma unroll
        for (int h0 = 0; h0 < 16; ++h0) {
            const float4 yv = *(const float4*)&y_s[px2 * 68 + h0 * 4];
#pragma unroll
            for (int it = 0; it < 4; ++it) {
                const float4 wv = *(const float4*)&wo_s[(cl + 32 * it) * 68 + h0 * 4];
                o[it] = fmaf(wv.x, yv.x, o[it]);
                o[it] = fmaf(wv.y, yv.y, o[it]);
                o[it] = fmaf(wv.z, yv.z, o[it]);
                o[it] = fmaf(wv.w, yv.w, o[it]);
            }
        }
#pragma unroll
        for (int it = 0; it < 4; ++it) {
            const size_t ccg = (size_t)(b * CCH + cl + 32 * it);
            const float xi = x[ccg * TT * HWPIX + gpix2];
            out[ccg * HWPIX + gpix2] = xi + o[it];
        }
    }
}

// ---------------------------------------------------------------------------
extern "C" void kernel_launch(void* const* d_in, const int* in_sizes, int n_in,
                              void* d_out, int out_size, void* d_ws, size_t ws_size,
                              hipStream_t stream)
{
    const float* x       = (const float*)d_in[0];
    const float* w_theta = (const float*)d_in[1];
    const float* w_phi   = (const float*)d_in[2];
    const float* w_g     = (const float*)d_in[3];
    const float* w_out   = (const float*)d_in[4];
    float* out = (float*)d_out;

    bf16_t* q_b   = (bf16_t*)d_ws;                        // 294912 elems
    bf16_t* phi_b = q_b + (size_t)BATCH * HWPIX * NHEAD;  // 2x 1179648 elems
    bf16_t* g_b   = phi_b + (size_t)GOFF;

    dim3 g1(HWPIX / 32, BATCH * TT);            // (72, 10)
    proj_kernel<<<g1, 256, 0, stream>>>(x, w_theta, w_phi, w_g, q_b, phi_b, g_b);

    dim3 g2(WW / TW, HH / TH, BATCH);           // (12, 24, 2) = 576 blocks
    attn_fused_kernel<<<g2, 256, 0, stream>>>(x, q_b, phi_b, w_out, out);
}

// Round 9
// 87.229 us; speedup vs baseline: 2.1797x; 1.0173x over previous
//
#include <hip/hip_runtime.h>
#include <hip/hip_bf16.h>
#include <math.h>

// B=2, C=128, T=5 (Tc=4 ctx), H=W=48, heads=64, PATCH=7 (pad 3), K=196.
#define BATCH 2
#define CCH 128
#define TT 5
#define TC 4
#define HH 48
#define WW 48
#define HWPIX 2304
#define NHEAD 64
#define PAD 3
#define XSTRIDE (TT*HWPIX)      // per-channel stride in x
#define PLANE (HWPIX*NHEAD)     // elements per UNPADDED (b,t) phi/g plane
#define GOFF (BATCH*TC*PLANE)   // g planes offset from phi planes (elements)

// fused-attn tile geometry: 4 wide x 2 tall pixel tile
#define TW 4
#define TH 2
#define WROWS 8                 // TH + 6
#define WCOLS 10                // TW + 6
#define NRC 80                  // WROWS*WCOLS
#define WELEM (NRC*NHEAD)       // 5120 bf16 per window buffer

#define WPITCH 136              // proj LDS pitch (bf16): 272B rows -> 2-way bank alias (free)

typedef unsigned short bf16_t;

static __device__ __forceinline__ bf16_t f2bf(float f) {
    unsigned u = __float_as_uint(f);
    u += 0x7FFFu + ((u >> 16) & 1u);          // round-to-nearest-even
    return (bf16_t)(u >> 16);
}
static __device__ __forceinline__ float bf_lo(unsigned u) {
    return __uint_as_float(u << 16);
}
static __device__ __forceinline__ float bf_hi(unsigned u) {
    return __uint_as_float(u & 0xFFFF0000u);
}
static __device__ __forceinline__ int iclamp(int v, int lo, int hi) {
    return v < lo ? lo : (v > hi ? hi : v);
}

// v_dot2_f32_bf16 path (hedged: falls back to unpack+fma if unavailable)
#if defined(__has_builtin)
#if __has_builtin(__builtin_amdgcn_fdot2_f32_bf16) && __has_builtin(__builtin_amdgcn_perm)
#define HAVE_DOT2 1
#endif
#endif

#ifdef HAVE_DOT2
typedef __bf16 bf16x2_t __attribute__((ext_vector_type(2)));
static __device__ __forceinline__ float dot2bf(unsigned g2, unsigned a2, float c) {
    return __builtin_amdgcn_fdot2_f32_bf16(
        __builtin_bit_cast(bf16x2_t, g2), __builtin_bit_cast(bf16x2_t, a2), c, false);
}
static __device__ __forceinline__ unsigned perm_lo(unsigned a, unsigned b) {
    return __builtin_amdgcn_perm(a, b, 0x05040100u);
}
static __device__ __forceinline__ unsigned perm_hi(unsigned a, unsigned b) {
    return __builtin_amdgcn_perm(a, b, 0x07060302u);
}
#else
static __device__ __forceinline__ float dot2bf(unsigned g2, unsigned a2, float c) {
    return c + bf_lo(g2) * bf_lo(a2) + bf_hi(g2) * bf_hi(a2);
}
#endif

typedef __attribute__((ext_vector_type(8))) short bf16x8;
typedef __attribute__((ext_vector_type(4))) float f32x4;

// ---------------------------------------------------------------------------
// K1: projections — MFMA, 64-px blocks (R9). Halves weight-staging traffic
// (50->25 MB L2 fp32 reads) and per-block fixed cost vs R8's 32-px blocks.
// Wave wv = px-tile (4 x 16 px); each wave computes all 4 h-tiles.
// Fragment layouts as verified (m89/m91/m92): A/B row=lane&15, k=(lane>>4)*8;
// D col=lane&15 (h), row=(lane>>4)*4+reg (px). LDS 51 KB -> 3 blocks/CU.
// ---------------------------------------------------------------------------
__global__ __launch_bounds__(256) void proj_kernel(
    const float* __restrict__ x,
    const float* __restrict__ w_theta,
    const float* __restrict__ w_phi,
    const float* __restrict__ w_g,
    bf16_t* __restrict__ q_b,
    bf16_t* __restrict__ phi_b,
    bf16_t* __restrict__ g_b)
{
    __shared__ bf16_t xs[64 * WPITCH];      // 17.4 KB [px][c]
    __shared__ bf16_t wla[64 * WPITCH];     // 17.4 KB [h][c]  theta/phi
    __shared__ bf16_t wlb[64 * WPITCH];     // 17.4 KB [h][c]  g

    const int bt   = blockIdx.y;        // 0..9
    const int b    = bt / TT;
    const int t    = bt % TT;
    const int tid  = threadIdx.x;
    const int lane = tid & 63;
    const int wv   = tid >> 6;          // 0..3 = 16-px tile
    const int p0   = blockIdx.x * 64;

    // ---- stage weights from fp32, packing to bf16 [h][c] rows ----
    {
        const float* srcA = (t == 0) ? w_theta : w_phi;
#pragma unroll
        for (int i = 0; i < 4; ++i) {
            const int idx = i * 256 + tid;   // 0..1023
            const int h   = idx >> 4;        // 0..63
            const int ck  = idx & 15;        // chunk 0..15
            const float* s = srcA + h * CCH + ck * 8;
            const float4 v0 = *(const float4*)(s);
            const float4 v1 = *(const float4*)(s + 4);
            uint4 o;
            o.x = (unsigned)f2bf(v0.x) | ((unsigned)f2bf(v0.y) << 16);
            o.y = (unsigned)f2bf(v0.z) | ((unsigned)f2bf(v0.w) << 16);
            o.z = (unsigned)f2bf(v1.x) | ((unsigned)f2bf(v1.y) << 16);
            o.w = (unsigned)f2bf(v1.z) | ((unsigned)f2bf(v1.w) << 16);
            *(uint4*)&wla[h * WPITCH + ck * 8] = o;
        }
        if (t != 0) {
#pragma unroll
            for (int i = 0; i < 4; ++i) {
                const int idx = i * 256 + tid;
                const int h   = idx >> 4;
                const int ck  = idx & 15;
                const float* s = w_g + h * CCH + ck * 8;
                const float4 v0 = *(const float4*)(s);
                const float4 v1 = *(const float4*)(s + 4);
                uint4 o;
                o.x = (unsigned)f2bf(v0.x) | ((unsigned)f2bf(v0.y) << 16);
                o.y = (unsigned)f2bf(v0.z) | ((unsigned)f2bf(v0.w) << 16);
                o.z = (unsigned)f2bf(v1.x) | ((unsigned)f2bf(v1.y) << 16);
                o.w = (unsigned)f2bf(v1.z) | ((unsigned)f2bf(v1.w) << 16);
                *(uint4*)&wlb[h * WPITCH + ck * 8] = o;
            }
        }
    }

    // ---- stage x tile as bf16 [px][c] (lanes over 64 px: 256B coalesced) ----
    {
        const float* xsrc = x + ((size_t)(b * CCH) * TT + t) * HWPIX + p0;
#pragma unroll
        for (int i = 0; i < 16; ++i) {
            const int idx = i * 256 + tid;  // 0..4095
            const int cp  = idx >> 6;       // c-pair 0..63
            const int px  = idx & 63;
            const float a0 = xsrc[(size_t)(2 * cp)     * XSTRIDE + px];
            const float a1 = xsrc[(size_t)(2 * cp + 1) * XSTRIDE + px];
            *(unsigned*)&xs[px * WPITCH + 2 * cp] =
                (unsigned)f2bf(a0) | ((unsigned)f2bf(a1) << 16);
        }
    }
    __syncthreads();

    // ---- MFMA K-loop ----
    const int arow = wv * 16 + (lane & 15);
    const int koff = (lane >> 4) * 8;

    bf16x8 afr[4];
#pragma unroll
    for (int kk = 0; kk < 4; ++kk)
        afr[kk] = *(const bf16x8*)&xs[arow * WPITCH + koff + 32 * kk];

    const int hrow16 = lane & 15;              // B-frag row within h-tile
    const int prow_  = (lane >> 4) * 4;        // D row base (px within tile)
    const int hcol   = lane & 15;              // D col (h within 16-tile)

    if (t == 0) {
#pragma unroll
        for (int ht = 0; ht < 4; ++ht) {
            f32x4 acc = {0.f, 0.f, 0.f, 0.f};
#pragma unroll
            for (int kk = 0; kk < 4; ++kk) {
                const bf16x8 bfr = *(const bf16x8*)&wla[(ht * 16 + hrow16) * WPITCH + koff + 32 * kk];
                acc = __builtin_amdgcn_mfma_f32_16x16x32_bf16(afr[kk], bfr, acc, 0, 0, 0);
            }
            const int h = ht * 16 + hcol;
#pragma unroll
            for (int r = 0; r < 4; ++r) {
                const int px = p0 + wv * 16 + prow_ + r;
                q_b[((size_t)b * HWPIX + px) * NHEAD + h] = f2bf(acc[r]);
            }
        }
    } else {
        const size_t base = (size_t)(b * TC + (t - 1)) * PLANE;
#pragma unroll
        for (int pr = 0; pr < 2; ++pr) {
            const bf16_t* wl = pr ? wlb : wla;
            bf16_t* dst = pr ? g_b : phi_b;
#pragma unroll
            for (int ht = 0; ht < 4; ++ht) {
                f32x4 acc = {0.f, 0.f, 0.f, 0.f};
#pragma unroll
                for (int kk = 0; kk < 4; ++kk) {
                    const bf16x8 bfr = *(const bf16x8*)&wl[(ht * 16 + hrow16) * WPITCH + koff + 32 * kk];
                    acc = __builtin_amdgcn_mfma_f32_16x16x32_bf16(afr[kk], bfr, acc, 0, 0, 0);
                }
                const int h = ht * 16 + hcol;
#pragma unroll
                for (int r = 0; r < 4; ++r) {
                    const int px = p0 + wv * 16 + prow_ + r;
                    dst[base + (size_t)px * NHEAD + h] = f2bf(acc[r]);
                }
            }
        }
    }
}

// ---------------------------------------------------------------------------
// K2: FUSED attention + combine + out-proj + residual (R7/R8 structure).
// R9 change: DEFERRED SUM, isolated (the good piece of R6): per-lane l_part
// rescaled by the uniform sc, reduced ONCE after the t-loop — removes 20
// serial shfl (5 per t x 4 t) from every block's critical path. No defer-max
// branch, no w_out register prefetch (those caused R6's regression).
// ---------------------------------------------------------------------------
__global__ __launch_bounds__(256) void attn_fused_kernel(
    const float* __restrict__ x,
    const bf16_t* __restrict__ q_b,
    const bf16_t* __restrict__ pg,      // phi planes; g planes at pg + GOFF
    const float* __restrict__ w_out,
    float* __restrict__ out)
{
    __shared__ __align__(16) char smem[4 * WELEM * 2];  // 40960 B win / alias
    __shared__ float ls[8][52];
    __shared__ unsigned ls2[8][26];
    __shared__ unsigned prow[26];

    const int tid = threadIdx.x;
    const int px  = tid >> 5;           // 0..7 pixel of tile
    const int sub = tid & 31;
    const int Y0  = blockIdx.x * TW;
    const int X0  = blockIdx.y * TH;
    const int b   = blockIdx.z;
    const int rr  = px >> 2;
    const int cc  = px & 3;
    const int gpix  = (X0 + rr) * WW + Y0 + cc;
    const int pxoff = rr * WCOLS + cc;
    const int oct = sub >> 2;
    const int par = sub & 3;

    // ---- q fragments (64 h = 8 uint4), broadcast across 32 sub-lanes ----
    uint4 qu[8];
    {
        const uint4* qs = (const uint4*)(q_b + ((size_t)b * HWPIX + gpix) * NHEAD);
#pragma unroll
        for (int ch = 0; ch < 8; ++ch) qu[ch] = qs[ch];
    }

    if (tid < 25) {
        const int k0 = 2 * tid;
        const int k1 = (k0 + 1 < 49) ? k0 + 1 : 48;
        const unsigned r0 = (unsigned)((k0 / 7) * WCOLS + (k0 % 7));
        const unsigned r1 = (unsigned)((k1 / 7) * WCOLS + (k1 % 7));
        prow[tid] = r0 | (r1 << 16);
    }

    // ---- per-thread staging offsets: 1280 uint4 per stage = 5/thread.
    //      Replicate padding realized here: clamp window coords to [0,47]. ----
    int srcoff[5], lddst[5];
#pragma unroll
    for (int ii = 0; ii < 5; ++ii) {
        const int idx  = ii * 256 + tid;          // 0..1279
        const int isg  = (idx >= 640) ? 1 : 0;    // 0: phi, 1: g
        const int idx2 = idx - (isg ? 640 : 0);
        const int row  = idx2 >> 3;               // 0..79
        const int ch   = idx2 & 7;
        const int i    = row / WCOLS;
        const int c    = row - i * WCOLS;
        const int xr   = iclamp(X0 + i - PAD, 0, HH - 1);
        const int yc   = iclamp(Y0 + c - PAD, 0, WW - 1);
        srcoff[ii] = isg * GOFF + (xr * WW + yc) * NHEAD + ch * 8;
        lddst[ii]  = isg * (2 * WELEM) + row * NHEAD + (((ch + row) & 7) << 3);
    }

    bf16_t* winb = (bf16_t*)smem;   // [phi0 | phi1 | g0 | g1], 5120 elems each

    // ---- prologue: stage t=0 into parity 0 ----
    {
        const bf16_t* sp = pg + (size_t)(b * TC) * PLANE;
#pragma unroll
        for (int ii = 0; ii < 5; ++ii) {
            const uint4 v = *(const uint4*)(sp + srcoff[ii]);
            *(uint4*)(winb + lddst[ii]) = v;
        }
    }
    __syncthreads();

    float m_run = -INFINITY, l_part = 0.f;
    float acc[8];
#pragma unroll
    for (int e = 0; e < 8; ++e) acc[e] = 0.f;

    for (int t = 0; t < TC; ++t) {
        const int p = t & 1;

        // ---- issue next-t loads early (hidden under logits+PV) ----
        uint4 stg[5];
        if (t < TC - 1) {
            const bf16_t* sp = pg + (size_t)(b * TC + t + 1) * PLANE;
#pragma unroll
            for (int ii = 0; ii < 5; ++ii)
                stg[ii] = *(const uint4*)(sp + srcoff[ii]);
        }

        __builtin_amdgcn_s_setprio(1);

        // ---- logits: keys k = sub and sub+32 ----
        const bf16_t* pbase = winb + p * WELEM;
        float v0, v1 = -INFINITY;
        {
            const int k = sub;
            const int i = k / 7, j = k - i * 7;
            const int row = i * WCOLS + j + pxoff;
            const bf16_t* base = pbase + row * NHEAD;
            float s = 0.f;
#pragma unroll
            for (int ch = 0; ch < 8; ++ch) {
                const uint4 u = *(const uint4*)&base[((ch + row) & 7) << 3];
                s = dot2bf(u.x, qu[ch].x, s);
                s = dot2bf(u.y, qu[ch].y, s);
                s = dot2bf(u.z, qu[ch].z, s);
                s = dot2bf(u.w, qu[ch].w, s);
            }
            v0 = s * 8.0f;    // * sqrt(64)
        }
        if (sub + 32 < 49) {
            const int k = sub + 32;
            const int i = k / 7, j = k - i * 7;
            const int row = i * WCOLS + j + pxoff;
            const bf16_t* base = pbase + row * NHEAD;
            float s = 0.f;
#pragma unroll
            for (int ch = 0; ch < 8; ++ch) {
                const uint4 u = *(const uint4*)&base[((ch + row) & 7) << 3];
                s = dot2bf(u.x, qu[ch].x, s);
                s = dot2bf(u.y, qu[ch].y, s);
                s = dot2bf(u.z, qu[ch].z, s);
                s = dot2bf(u.w, qu[ch].w, s);
            }
            v1 = s * 8.0f;
        }

        // ---- online softmax: max reduce per t; SUM DEFERRED to epilogue ----
        float mt = fmaxf(v0, v1);
#pragma unroll
        for (int d = 1; d < 32; d <<= 1) mt = fmaxf(mt, __shfl_xor(mt, d));
        const float m_new = fmaxf(m_run, mt);
        const float sc = __expf(m_run - m_new);
        const float e0 = __expf(v0 - m_new);
        float lp = e0;
        ls[px][sub] = e0;
        if (sub + 32 < 49) {
            const float e1 = __expf(v1 - m_new);
            ls[px][sub + 32] = e1;
            lp += e1;
        }
        l_part = l_part * sc + lp;
        m_run = m_new;

        if (sub < 25) {
            const float a0 = ls[px][2 * sub];
            const float a1 = (2 * sub + 1 < 49) ? ls[px][2 * sub + 1] : 0.f;
            ls2[px][sub] = (unsigned)f2bf(a0) | ((unsigned)f2bf(a1) << 16);
        }

        // ---- PV accumulate with rescale ----
#pragma unroll
        for (int e = 0; e < 8; ++e) acc[e] *= sc;
        const bf16_t* gbase = winb + 2 * WELEM + p * WELEM;
#pragma unroll
        for (int mi = 0; mi < 7; ++mi) {
            const int pm = par + 4 * mi;
            if (pm < 25) {
                const unsigned pr = prow[pm];
                const int row0 = (int)(pr & 0xFFFFu) + pxoff;
                const int row1 = (int)(pr >> 16) + pxoff;
                const uint4 u0 = *(const uint4*)&gbase[row0 * NHEAD + (((oct + row0) & 7) << 3)];
                const uint4 u1 = *(const uint4*)&gbase[row1 * NHEAD + (((oct + row1) & 7) << 3)];
#ifdef HAVE_DOT2
                const unsigned a2 = ls2[px][pm];
                acc[0] = dot2bf(perm_lo(u1.x, u0.x), a2, acc[0]);
                acc[1] = dot2bf(perm_hi(u1.x, u0.x), a2, acc[1]);
                acc[2] = dot2bf(perm_lo(u1.y, u0.y), a2, acc[2]);
                acc[3] = dot2bf(perm_hi(u1.y, u0.y), a2, acc[3]);
                acc[4] = dot2bf(perm_lo(u1.z, u0.z), a2, acc[4]);
                acc[5] = dot2bf(perm_hi(u1.z, u0.z), a2, acc[5]);
                acc[6] = dot2bf(perm_lo(u1.w, u0.w), a2, acc[6]);
                acc[7] = dot2bf(perm_hi(u1.w, u0.w), a2, acc[7]);
#else
                const float a0 = ls[px][2 * pm];
                const float a1 = (2 * pm + 1 < 49) ? ls[px][2 * pm + 1] : 0.f;
                acc[0] = fmaf(a1, bf_lo(u1.x), fmaf(a0, bf_lo(u0.x), acc[0]));
                acc[1] = fmaf(a1, bf_hi(u1.x), fmaf(a0, bf_hi(u0.x), acc[1]));
                acc[2] = fmaf(a1, bf_lo(u1.y), fmaf(a0, bf_lo(u0.y), acc[2]));
                acc[3] = fmaf(a1, bf_hi(u1.y), fmaf(a0, bf_hi(u0.y), acc[3]));
                acc[4] = fmaf(a1, bf_lo(u1.z), fmaf(a0, bf_lo(u0.z), acc[4]));
                acc[5] = fmaf(a1, bf_hi(u1.z), fmaf(a0, bf_hi(u0.z), acc[5]));
                acc[6] = fmaf(a1, bf_lo(u1.w), fmaf(a0, bf_lo(u0.w), acc[6]));
                acc[7] = fmaf(a1, bf_hi(u1.w), fmaf(a0, bf_hi(u0.w), acc[7]));
#endif
            }
        }

        __builtin_amdgcn_s_setprio(0);

        // ---- write-late: next-t windows into alternate buffers ----
        if (t < TC - 1) {
            bf16_t* dp = winb + (p ^ 1) * WELEM;   // g offset baked into lddst
#pragma unroll
            for (int ii = 0; ii < 5; ++ii)
                *(uint4*)(dp + lddst[ii]) = stg[ii];
        }
        __syncthreads();
    }

    // ---- deferred l reduce (once), then par reduce of acc ----
#pragma unroll
    for (int d = 1; d < 32; d <<= 1) l_part += __shfl_xor(l_part, d);
#pragma unroll
    for (int e = 0; e < 8; ++e) {
        acc[e] += __shfl_xor(acc[e], 1);
        acc[e] += __shfl_xor(acc[e], 2);
    }
    const float inv = 1.0f / l_part;

    // ---- epilogue: alias win LDS as w_out tile + y tile ----
    float* wo_s = (float*)smem;                        // [128][68] = 34816 B
    float* y_s  = (float*)(smem + 128 * 68 * 4);       // [8][68]   =  2176 B

#pragma unroll
    for (int ii = 0; ii < 8; ++ii) {
        const int idx = ii * 256 + tid;    // 0..2047
        const int c   = idx >> 4;
        const int hq  = idx & 15;
        const float4 v = *(const float4*)(w_out + (size_t)c * NHEAD + hq * 4);
        *(float4*)&wo_s[c * 68 + hq * 4] = v;
    }
    if (par == 0) {
        const float4 o0 = make_float4(acc[0] * inv, acc[1] * inv, acc[2] * inv, acc[3] * inv);
        const float4 o1 = make_float4(acc[4] * inv, acc[5] * inv, acc[6] * inv, acc[7] * inv);
        *(float4*)&y_s[px * 68 + oct * 8]     = o0;
        *(float4*)&y_s[px * 68 + oct * 8 + 4] = o1;
    }
    __syncthreads();

    // ---- out-projection + residual ----
    {
        const int px2 = tid & 7;
        const int cl  = tid >> 3;          // 0..31
        const int rr2 = px2 >> 2, cc2 = px2 & 3;
        const int gpix2 = (X0 + rr2) * WW + Y0 + cc2;
        float o[4] = {0.f, 0.f, 0.f, 0.f};
#pragma unroll
        for (int h0 = 0; h0 < 16; ++h0) {
            const float4 yv = *(const float4*)&y_s[px2 * 68 + h0 * 4];
#pragma unroll
            for (int it = 0; it < 4; ++it) {
                const float4 wv = *(const float4*)&wo_s[(cl + 32 * it) * 68 + h0 * 4];
                o[it] = fmaf(wv.x, yv.x, o[it]);
                o[it] = fmaf(wv.y, yv.y, o[it]);
                o[it] = fmaf(wv.z, yv.z, o[it]);
                o[it] = fmaf(wv.w, yv.w, o[it]);
            }
        }
#pragma unroll
        for (int it = 0; it < 4; ++it) {
            const size_t ccg = (size_t)(b * CCH + cl + 32 * it);
            const float xi = x[ccg * TT * HWPIX + gpix2];
            out[ccg * HWPIX + gpix2] = xi + o[it];
        }
    }
}

// ---------------------------------------------------------------------------
extern "C" void kernel_launch(void* const* d_in, const int* in_sizes, int n_in,
                              void* d_out, int out_size, void* d_ws, size_t ws_size,
                              hipStream_t stream)
{
    const float* x       = (const float*)d_in[0];
    const float* w_theta = (const float*)d_in[1];
    const float* w_phi   = (const float*)d_in[2];
    const float* w_g     = (const float*)d_in[3];
    const float* w_out   = (const float*)d_in[4];
    float* out = (float*)d_out;

    bf16_t* q_b   = (bf16_t*)d_ws;                        // 294912 elems
    bf16_t* phi_b = q_b + (size_t)BATCH * HWPIX * NHEAD;  // 2x 1179648 elems
    bf16_t* g_b   = phi_b + (size_t)GOFF;

    dim3 g1(HWPIX / 64, BATCH * TT);            // (36, 10)
    proj_kernel<<<g1, 256, 0, stream>>>(x, w_theta, w_phi, w_g, q_b, phi_b, g_b);

    dim3 g2(WW / TW, HH / TH, BATCH);           // (12, 24, 2) = 576 blocks
    attn_fused_kernel<<<g2, 256, 0, stream>>>(x, q_b, phi_b, w_out, out);
}